// Round 1
// 444.513 us; speedup vs baseline: 1.0414x; 1.0414x over previous
//
#include <hip/hip_runtime.h>
#include <cfloat>

// =====================================================================
// VQ-VAE forward.
// R10: k_conv2m -> k_conv2s: weights staged in LDS (96 KB = one s-half
// of the NP=3 split weight set), 1024-thread blocks (16 waves, 1
// block/CU, 4 waves/SIMD). R9 counters showed conv2m issue-bound:
// MfmaUtil 17%, HBM 21%, occupancy 36% -- 12 of 15 global loads per
// s-iter were re-reads of a 196 KB weight tensor (786 MB of L1/L2
// traffic). LDS staging cuts global loads to 3/s (A planes only).
// Numerically bit-identical to R9 (same MFMA order/operands).
//
// conv_transpose (transpose_kernel=False) => flipped kernel:
//   out[4i+r, 4j+u, o] = sum_c in[i,j,c] * w[3-r, 3-u, c, o]
// Encoder convs: SAME pad = (1,1) -> padded split inputs.
// Precision: NP=3 split (6 MFMA products) ~= fp32 (2^-25 rel) for
// everything feeding the argmin; NP=2 (3 products, ~1e-5 rel) for the
// decoder (threshold 2.5e-4).
// =====================================================================

typedef short bf16x8 __attribute__((ext_vector_type(8)));
typedef float f32x4 __attribute__((ext_vector_type(4)));
#define MFMA16(a, b, c) __builtin_amdgcn_mfma_f32_16x16x32_bf16(a, b, c, 0, 0, 0)

__device__ inline unsigned short f2bf(float x) {  // RNE, inputs finite
  unsigned u = __float_as_uint(x);
  u += 0x7fffu + ((u >> 16) & 1u);
  return (unsigned short)(u >> 16);
}
__device__ inline float bf2f(unsigned short h) {
  return __uint_as_float(((unsigned)h) << 16);
}
__device__ inline void split3v(float v, unsigned short& hb, unsigned short& mb,
                               unsigned short& lb) {
  hb = f2bf(v);
  float r1 = v - bf2f(hb);
  mb = f2bf(r1);
  lb = f2bf(r1 - bf2f(mb));
}

// ---------------- fused input-only prep (one launch) ----------------
// segments: zborder h1p | zborder h2p | wprep2 | wprep3 | eprep | norm2 |
// bprep dec_fc (NP2) | bprep_ct dec_w2 (NP2)
#define PB0 12672
#define PB1 (PB0 + 13056)
#define PB2 (PB1 + 128)
#define PB3 (PB2 + 512)
#define PB4 (PB3 + 2048)
#define PB5 (PB4 + 32)
#define PB6 (PB5 + 4096)
#define PB7 (PB6 + 2048)
__global__ __launch_bounds__(256) void k_prep_early(
    const float* __restrict__ enc_w2, const float* __restrict__ enc_w3,
    const float* __restrict__ embeds, const float* __restrict__ dec_fc_w,
    const float* __restrict__ dec_w2, unsigned short* __restrict__ h1base,
    unsigned short* __restrict__ h2base, unsigned short* __restrict__ Wp2H,
    unsigned short* __restrict__ Wp2M, unsigned short* __restrict__ Wp2L,
    unsigned short* __restrict__ Wp3H, unsigned short* __restrict__ Wp3M,
    unsigned short* __restrict__ Wp3L, unsigned short* __restrict__ eB,
    float* __restrict__ n2, unsigned short* __restrict__ Bp_dfc,
    unsigned short* __restrict__ Bp_d2) {
  int blk = blockIdx.x;
  int t = threadIdx.x;
  if (blk < PB0) {                       // zborder h1p (W=34, C=32)
    int li = blk * 256 + t;
    int bc = li & 8191;
    int rest = li >> 13;                 // i + 132*plane
    int i = rest % 132, plane = rest / 132;
    int b = bc >> 5, c = bc & 31;
    int row, col;
    if (i < 34) { row = 0; col = i; }
    else if (i < 68) { row = 33; col = i - 34; }
    else { int j = i - 68; row = 1 + (j >> 1); col = (j & 1) ? 33 : 0; }
    h1base[(size_t)plane * 9469952 + ((size_t)(b * 34 + row) * 34 + col) * 32 + c] = 0;
  } else if (blk < PB1) {                // zborder h2p (W=18, C=64)
    int li = (blk - PB0) * 256 + t;
    int bc = li & 16383;
    int rest = li >> 14;
    int i = rest % 68, plane = rest / 68;
    int b = bc >> 6, c = bc & 63;
    int row, col;
    if (i < 18) { row = 0; col = i; }
    else if (i < 36) { row = 17; col = i - 18; }
    else { int j = i - 36; row = 1 + (j >> 1); col = (j & 1) ? 17 : 0; }
    h2base[(size_t)plane * 5308416 + ((size_t)(b * 18 + row) * 18 + col) * 64 + c] = 0;
  } else if (blk < PB2) {                // wprep2
    int idx = (blk - PB1) * 256 + t;     // 32768
    int j = idx & 7, lane = (idx >> 3) & 63, nt = (idx >> 9) & 3, s = idx >> 11;
    int ci = ((lane >> 4) << 3) + j, co = (nt << 4) + (lane & 15);
    unsigned short hb, mb, lb;
    split3v(enc_w2[(s * 32 + ci) * 64 + co], hb, mb, lb);
    Wp2H[idx] = hb; Wp2M[idx] = mb; Wp2L[idx] = lb;
  } else if (blk < PB3) {                // wprep3
    int idx = (blk - PB2) * 256 + t;     // 131072
    int j = idx & 7, lane = (idx >> 3) & 63, ks = (idx >> 9) & 1;
    int nt = (idx >> 10) & 3, ch = (idx >> 12) & 1, s = idx >> 13;
    int ci = ks * 32 + ((lane >> 4) << 3) + j;
    int co = ch * 64 + (nt << 4) + (lane & 15);
    unsigned short hb, mb, lb;
    split3v(enc_w3[(s * 64 + ci) * 128 + co], hb, mb, lb);
    Wp3H[idx] = hb; Wp3M[idx] = mb; Wp3L[idx] = lb;
  } else if (blk < PB4) {                // eprep (one read -> 3 writes)
    int idx = (blk - PB3) * 256 + t;     // 524,288
    int j = idx & 7, lane = (idx >> 3) & 63;
    int f = idx >> 9;                    // (kt*2+ks)*4+nt
    int nt = f & 3, ks = (f >> 2) & 1, kt = f >> 3;
    int code = kt * 64 + nt * 16 + (lane & 15);
    int k = ks * 32 + ((lane >> 4) << 3) + j;
    unsigned short hb, mb, lb;
    split3v(embeds[(size_t)code * 64 + k], hb, mb, lb);
    size_t base = (size_t)f * 1536 + lane * 8 + j;
    eB[base] = hb; eB[base + 512] = mb; eB[base + 1024] = lb;
  } else if (blk < PB5) {                // norm2
    int k = (blk - PB4) * 256 + t;       // 8192
    const float4* p = (const float4*)(embeds + (size_t)k * 64);
    float s0 = 0, s1 = 0, s2 = 0, s3 = 0;
#pragma unroll
    for (int j = 0; j < 16; ++j) {
      float4 v = p[j];
      s0 = fmaf(v.x, v.x, s0); s1 = fmaf(v.y, v.y, s1);
      s2 = fmaf(v.z, v.z, s2); s3 = fmaf(v.w, v.w, s3);
    }
    n2[k] = (s0 + s1) + (s2 + s3);
  } else if (blk < PB6) {                // bprep dec_fc NP=2 (K=2048,N=512)
    int idx = (blk - PB5) * 256 + t;     // 1,048,576
    int j = idx & 7, lane = (idx >> 3) & 63;
    int f = idx >> 9;
    int ntg = f & 31;                    // NT=32
    int kt = f >> 5;                     // KT=64
    int k = kt * 32 + ((lane >> 4) << 3) + j;
    int n = ntg * 16 + (lane & 15);
    unsigned short hb, mb, lb;
    split3v(dec_fc_w[(size_t)k * 512 + n], hb, mb, lb);
    Bp_dfc[idx] = hb; Bp_dfc[idx + 1048576] = mb;
  } else if (blk < PB7) {                // bprep_ct dec_w2 NP=2 (K=256,N=2048,CO=128)
    int idx = (blk - PB6) * 256 + t;     // 524,288
    int j = idx & 7, lane = (idx >> 3) & 63;
    int f = idx >> 9;
    int ntg = f & 127;                   // NT=128
    int kt = f >> 7;                     // KT=8
    int k = kt * 32 + ((lane >> 4) << 3) + j;
    int n = ntg * 16 + (lane & 15);
    int o = n & 127, ru = n >> 7;
    int r = ru >> 2, u = ru & 3;
    int sf = (3 - r) * 4 + (3 - u);
    unsigned short hb, mb, lb;
    split3v(dec_w2[(((size_t)sf * 256 + k) << 7) + o], hb, mb, lb);
    Bp_d2[idx] = hb; Bp_d2[idx + 524288] = mb;
  }
}

// ---------------- conv1: x(256,64,64,1) -> h1p split padded (256,34,34,32) ----
__global__ __launch_bounds__(256) void k_conv1(const float* __restrict__ x,
                                               const float* __restrict__ w,
                                               const float* __restrict__ bias,
                                               unsigned short* __restrict__ oH,
                                               unsigned short* __restrict__ oM,
                                               unsigned short* __restrict__ oL) {
  int b = blockIdx.x >> 5;          // 8192 blocks: (b, y)
  int y = blockIdx.x & 31;
  int t = threadIdx.x;
  int c = t & 31;
  int xg = t >> 5;                  // 0..7, 4 x-positions each
  float acc[4] = {0.f, 0.f, 0.f, 0.f};
  for (int dy = 0; dy < 4; ++dy) {
    int iy = 2 * y + dy - 1;
    if (iy < 0 || iy >= 64) continue;
    const float* xrow = x + ((size_t)b * 64 + iy) * 64;
    for (int dx = 0; dx < 4; ++dx) {
      float wv = w[(dy * 4 + dx) * 32 + c];
#pragma unroll
      for (int i = 0; i < 4; ++i) {
        int ix = 8 * xg + 2 * i + dx - 1;
        float v = (ix >= 0 && ix < 64) ? xrow[ix] : 0.f;
        acc[i] = fmaf(v, wv, acc[i]);
      }
    }
  }
  float bv = bias[c];
#pragma unroll
  for (int i = 0; i < 4; ++i) {
    float v = acc[i] + bv;
    v = v > 0.f ? v : 0.f;
    unsigned short hb, mb, lb;
    split3v(v, hb, mb, lb);
    size_t o = ((size_t)(b * 34 + y + 1) * 34 + (4 * xg + i + 1)) * 32 + c;
    oH[o] = hb; oM[o] = mb; oL[o] = lb;
  }
}

// ---------------- conv2 MFMA, LDS-staged weights ----------------
// 1024-thread blocks (16 waves), 256 blocks = 1 block/CU, 4 waves/SIMD.
// Bs holds one s-half of the NP=3 split weights: 3 planes x 8 s x 4 nt
// x 64 lanes x 8 shorts = 49152 shorts = 96 KB.
__global__ __launch_bounds__(1024, 4) void k_conv2s(
    const unsigned short* __restrict__ aH, const unsigned short* __restrict__ aM,
    const unsigned short* __restrict__ aL, const unsigned short* __restrict__ wH,
    const unsigned short* __restrict__ wM, const unsigned short* __restrict__ wL,
    const float* __restrict__ bias, unsigned short* __restrict__ oH,
    unsigned short* __restrict__ oM, unsigned short* __restrict__ oL) {
  __shared__ unsigned short Bs[49152];      // 96 KB
  int t = threadIdx.x;
  int wave = t >> 6, lane = t & 63;
  int l15 = lane & 15, quad = lane >> 4;
  int m0 = blockIdx.x * 256 + wave * 16;    // 256 blocks x 256 px
  int p = m0 + l15;
  int b = p >> 8, y = (p >> 4) & 15, x = p & 15;
  f32x4 acc[4] = {};
#pragma unroll
  for (int hf = 0; hf < 2; ++hf) {
    if (hf) __syncthreads();                // all waves done reading half 0
    // stage half hf: per plane 16384 shorts (= s in [8hf, 8hf+8))
    {
      const unsigned short* s0 = wH + hf * 16384;
      const unsigned short* s1 = wM + hf * 16384;
      const unsigned short* s2 = wL + hf * 16384;
#pragma unroll
      for (int i = 0; i < 2; ++i) {
        int o8 = (i * 1024 + t) * 8;
        *(bf16x8*)(Bs + o8)         = *(const bf16x8*)(s0 + o8);
        *(bf16x8*)(Bs + 16384 + o8) = *(const bf16x8*)(s1 + o8);
        *(bf16x8*)(Bs + 32768 + o8) = *(const bf16x8*)(s2 + o8);
      }
    }
    __syncthreads();
#pragma unroll 4
    for (int sl = 0; sl < 8; ++sl) {
      int s = hf * 8 + sl;
      int dy = s >> 2, dx = s & 3;
      size_t aoff = ((size_t)(b * 34 + 2 * y + dy) * 34 + (2 * x + dx)) * 32 + quad * 8;
      bf16x8 ah = *(const bf16x8*)(aH + aoff);
      bf16x8 am = *(const bf16x8*)(aM + aoff);
      bf16x8 al = *(const bf16x8*)(aL + aoff);
#pragma unroll
      for (int nt = 0; nt < 4; ++nt) {
        const unsigned short* bp = Bs + ((sl * 4 + nt) * 64 + lane) * 8;
        bf16x8 bh = *(const bf16x8*)(bp);
        bf16x8 bm = *(const bf16x8*)(bp + 16384);
        bf16x8 bl = *(const bf16x8*)(bp + 32768);
        acc[nt] = MFMA16(am, bm, acc[nt]);
        acc[nt] = MFMA16(ah, bl, acc[nt]);
        acc[nt] = MFMA16(al, bh, acc[nt]);
        acc[nt] = MFMA16(ah, bm, acc[nt]);
        acc[nt] = MFMA16(am, bh, acc[nt]);
        acc[nt] = MFMA16(ah, bh, acc[nt]);
      }
    }
  }
#pragma unroll
  for (int r = 0; r < 4; ++r) {
    int pp = m0 + quad * 4 + r;
    int b2 = pp >> 8, yo = (pp >> 4) & 15, xo = pp & 15;
    size_t obase = ((size_t)(b2 * 18 + yo + 1) * 18 + (xo + 1)) * 64;
#pragma unroll
    for (int nt = 0; nt < 4; ++nt) {
      int co = nt * 16 + l15;
      float v = acc[nt][r] + bias[co];
      v = v > 0.f ? v : 0.f;
      unsigned short hb, mb, lb;
      split3v(v, hb, mb, lb);
      oH[obase + co] = hb; oM[obase + co] = mb; oL[obase + co] = lb;
    }
  }
}

// ---------------- conv3 MFMA -> fp32 partials [z][16384][128] ----------------
// grid (512, 2): 32 px x 128 co per block; wave = 16 px x 64 co; z = s-half.
__global__ __launch_bounds__(256, 4) void k_conv3m(
    const unsigned short* __restrict__ aH, const unsigned short* __restrict__ aM,
    const unsigned short* __restrict__ aL, const unsigned short* __restrict__ wH,
    const unsigned short* __restrict__ wM, const unsigned short* __restrict__ wL,
    float* __restrict__ part) {
  int t = threadIdx.x;
  int wave = t >> 6, lane = t & 63;
  int l15 = lane & 15, quad = lane >> 4;
  int mtg = wave & 1, ch = wave >> 1;
  int m0 = blockIdx.x * 32 + mtg * 16;
  int z = blockIdx.y;
  int p = m0 + l15;
  int b = p >> 6, y = (p >> 3) & 7, x = p & 7;
  f32x4 acc[4] = {};
#pragma unroll 2
  for (int si = 0; si < 8; ++si) {
    int s = z * 8 + si;
    int dy = s >> 2, dx = s & 3;
    size_t base = ((size_t)(b * 18 + 2 * y + dy) * 18 + (2 * x + dx)) * 64 + quad * 8;
    bf16x8 ah[2], am[2], al[2];
#pragma unroll
    for (int ks = 0; ks < 2; ++ks) {
      ah[ks] = *(const bf16x8*)(aH + base + ks * 32);
      am[ks] = *(const bf16x8*)(aM + base + ks * 32);
      al[ks] = *(const bf16x8*)(aL + base + ks * 32);
    }
#pragma unroll
    for (int nt = 0; nt < 4; ++nt) {
#pragma unroll
      for (int ks = 0; ks < 2; ++ks) {
        size_t woff = ((size_t)((((s * 2 + ch) * 4 + nt) * 2 + ks) * 64 + lane)) * 8;
        bf16x8 bh = *(const bf16x8*)(wH + woff);
        bf16x8 bm = *(const bf16x8*)(wM + woff);
        bf16x8 bl = *(const bf16x8*)(wL + woff);
        acc[nt] = MFMA16(am[ks], bm, acc[nt]);
        acc[nt] = MFMA16(ah[ks], bl, acc[nt]);
        acc[nt] = MFMA16(al[ks], bh, acc[nt]);
        acc[nt] = MFMA16(ah[ks], bm, acc[nt]);
        acc[nt] = MFMA16(am[ks], bh, acc[nt]);
        acc[nt] = MFMA16(ah[ks], bh, acc[nt]);
      }
    }
  }
  float* Cp = part + (size_t)z * 2097152;
#pragma unroll
  for (int nt = 0; nt < 4; ++nt) {
    int co = ch * 64 + nt * 16 + l15;
#pragma unroll
    for (int r = 0; r < 4; ++r) {
      int pp = m0 + quad * 4 + r;
      Cp[(size_t)pp * 128 + co] = acc[nt][r];
    }
  }
}

// ---------------- fused: sumrelu(conv3) + bprep fc (NP=3) ----------------
#define FB0 8192
#define FB1 (FB0 + 16384)
__global__ __launch_bounds__(256) void k_prep_fc(
    const float* __restrict__ part, const float* __restrict__ enc_b3,
    unsigned short* __restrict__ h3H, unsigned short* __restrict__ h3M,
    unsigned short* __restrict__ h3L, const float* __restrict__ fc_w,
    unsigned short* __restrict__ Bp_fc) {
  int blk = blockIdx.x;
  int t = threadIdx.x;
  if (blk < FB0) {                       // sumrelu conv3: MN=2097152, S=2
    int idx = blk * 256 + t;
    float s = part[idx] + part[2097152 + idx] + enc_b3[idx & 127];
    s = s > 0.f ? s : 0.f;
    unsigned short hb, mb, lb;
    split3v(s, hb, mb, lb);
    h3H[idx] = hb; h3M[idx] = mb; h3L[idx] = lb;
  } else {                               // bprep fc: K=8192, N=512 (KT=256,NT=32)
    int idx = (blk - FB0) * 256 + t;     // 4,194,304
    int j = idx & 7, lane = (idx >> 3) & 63;
    int f = idx >> 9;
    int ntg = f & 31;
    int kt = f >> 5;
    int k = kt * 32 + ((lane >> 4) << 3) + j;
    int n = ntg * 16 + (lane & 15);
    unsigned short hb, mb, lb;
    split3v(fc_w[(size_t)k * 512 + n], hb, mb, lb);
    Bp_fc[idx] = hb; Bp_fc[idx + 4194304] = mb; Bp_fc[idx + 8388608] = lb;
  }
}

// ---------------- fused: bprep ffc (NP=3) + bprep_ct dec_w1 (NP=2) ----------
#define WB0 4096
#define WB1 (WB0 + 8192)
__global__ __launch_bounds__(256) void k_prep_w2(
    const float* __restrict__ ffc_w, unsigned short* __restrict__ Bp_ffc,
    const float* __restrict__ dec_w1, unsigned short* __restrict__ Bp_d1) {
  int blk = blockIdx.x;
  int t = threadIdx.x;
  if (blk < WB0) {                       // ffc: K=512, N=2048 (KT=16, NT=128)
    int idx = blk * 256 + t;             // 1,048,576
    int j = idx & 7, lane = (idx >> 3) & 63;
    int f = idx >> 9;
    int ntg = f & 127;
    int kt = f >> 7;
    int k = kt * 32 + ((lane >> 4) << 3) + j;
    int n = ntg * 16 + (lane & 15);
    unsigned short hb, mb, lb;
    split3v(ffc_w[(size_t)k * 2048 + n], hb, mb, lb);
    Bp_ffc[idx] = hb; Bp_ffc[idx + 1048576] = mb; Bp_ffc[idx + 2097152] = lb;
  } else {                               // dec_w1 ct: K=512, N=4096, CO=256
    int idx = (blk - WB0) * 256 + t;     // 2,097,152
    int j = idx & 7, lane = (idx >> 3) & 63;
    int f = idx >> 9;
    int ntg = f & 255;                   // NT=256
    int kt = f >> 8;                     // KT=16
    int k = kt * 32 + ((lane >> 4) << 3) + j;
    int n = ntg * 16 + (lane & 15);
    int o = n & 255, ru = n >> 8;
    int r = ru >> 2, u = ru & 3;
    int sf = (3 - r) * 4 + (3 - u);
    unsigned short hb, mb, lb;
    split3v(dec_w1[(((size_t)sf * 512 + k) << 8) + o], hb, mb, lb);
    Bp_d1[idx] = hb; Bp_d1[idx + 2097152] = mb;
  }
}

// ---------------- generic split-bf16 MFMA GEMM ----------------
template <int NP, int NTW>
__global__ __launch_bounds__(256) void k_mgemm(
    const unsigned short* __restrict__ A0, const unsigned short* __restrict__ A1,
    const unsigned short* __restrict__ A2, const unsigned short* __restrict__ Bp,
    float* __restrict__ C, const float* __restrict__ bias,
    int M, int N, int K, int bmask) {
  int S = gridDim.z;
  int Kc = K / S;
  int t = threadIdx.x;
  int wave = t >> 6, lane = t & 63;
  int l15 = lane & 15, quad = lane >> 4;
  int m0 = blockIdx.x * 64 + wave * 16;
  int n0 = blockIdx.y * (16 * NTW);
  int KT = K >> 5, NT = N >> 4;
  int kt0 = (blockIdx.z * Kc) >> 5;
  int ktn = Kc >> 5;
  size_t sstride = (size_t)KT * NT * 512;
  const unsigned short* arow0 = A0 + (size_t)(m0 + l15) * K + quad * 8;
  const unsigned short* arow1 = A1 + (size_t)(m0 + l15) * K + quad * 8;
  const unsigned short* arow2 = nullptr;
  if constexpr (NP == 3) arow2 = A2 + (size_t)(m0 + l15) * K + quad * 8;
  f32x4 acc[NTW] = {};
  for (int kt = kt0; kt < kt0 + ktn; ++kt) {
    bf16x8 ah = *(const bf16x8*)(arow0 + kt * 32);
    bf16x8 am = *(const bf16x8*)(arow1 + kt * 32);
    bf16x8 al;
    if constexpr (NP == 3) al = *(const bf16x8*)(arow2 + kt * 32);
    const unsigned short* bbase =
        Bp + ((size_t)kt * NT + (n0 >> 4)) * 512 + lane * 8;
#pragma unroll
    for (int nt = 0; nt < NTW; ++nt) {
      const unsigned short* bp = bbase + nt * 512;
      bf16x8 bh = *(const bf16x8*)(bp);
      bf16x8 bm = *(const bf16x8*)(bp + sstride);
      if constexpr (NP == 3) {
        bf16x8 bl = *(const bf16x8*)(bp + 2 * sstride);
        acc[nt] = MFMA16(am, bm, acc[nt]);
        acc[nt] = MFMA16(ah, bl, acc[nt]);
        acc[nt] = MFMA16(al, bh, acc[nt]);
        acc[nt] = MFMA16(ah, bm, acc[nt]);
        acc[nt] = MFMA16(am, bh, acc[nt]);
        acc[nt] = MFMA16(ah, bh, acc[nt]);
      } else {
        acc[nt] = MFMA16(ah, bm, acc[nt]);
        acc[nt] = MFMA16(am, bh, acc[nt]);
        acc[nt] = MFMA16(ah, bh, acc[nt]);
      }
    }
  }
  if (S == 1) {
#pragma unroll
    for (int nt = 0; nt < NTW; ++nt) {
      int n = n0 + nt * 16 + l15;
      float bv = bias[n & bmask];
#pragma unroll
      for (int r = 0; r < 4; ++r) {
        int m = m0 + quad * 4 + r;
        float v = acc[nt][r] + bv;
        C[(size_t)m * N + n] = v > 0.f ? v : 0.f;
      }
    }
  } else {
    float* Cp = C + (size_t)blockIdx.z * M * N;
#pragma unroll
    for (int nt = 0; nt < NTW; ++nt) {
      int n = n0 + nt * 16 + l15;
#pragma unroll
      for (int r = 0; r < 4; ++r) {
        int m = m0 + quad * 4 + r;
        Cp[(size_t)m * N + n] = acc[nt][r];
      }
    }
  }
}

// sum k-split partials + bias + relu -> split planes
template <int NPOUT>
__global__ __launch_bounds__(256) void k_sumrelu3(
    const float* __restrict__ part, const float* __restrict__ bias,
    unsigned short* __restrict__ oH, unsigned short* __restrict__ oM,
    unsigned short* __restrict__ oL, int MN, int bmask, int S) {
  int idx = blockIdx.x * 256 + threadIdx.x;
  float s = 0.f;
  for (int z = 0; z < S; ++z) s += part[(size_t)z * MN + idx];
  s += bias[idx & bmask];
  s = s > 0.f ? s : 0.f;
  unsigned short hb = f2bf(s);
  float r1 = s - bf2f(hb);
  unsigned short mb = f2bf(r1);
  oH[idx] = hb; oM[idx] = mb;
  if constexpr (NPOUT == 3) oL[idx] = f2bf(r1 - bf2f(mb));
}

// ---------------- VQ ----------------
// k_vqmfma3: 32 m-rows per wave (2 A-sets), codes streamed as B-frags.
__global__ __launch_bounds__(256) void k_vqmfma3(
    const unsigned short* __restrict__ pH, const unsigned short* __restrict__ pM,
    const unsigned short* __restrict__ pL, const unsigned short* __restrict__ eB,
    const float* __restrict__ n2, float* __restrict__ pbd, int* __restrict__ pbk) {
  int t = threadIdx.x;
  int wave = t >> 6, lane = t & 63;
  int l15 = lane & 15, quad = lane >> 4;
  int m0 = blockIdx.x * 128 + wave * 32;
  int z = blockIdx.y;
  bf16x8 ah[2][2], am[2][2], al[2][2];   // [mt][ks]
#pragma unroll
  for (int mt = 0; mt < 2; ++mt) {
    size_t arow = (size_t)(m0 + mt * 16 + l15) * 64 + quad * 8;
#pragma unroll
    for (int ks = 0; ks < 2; ++ks) {
      ah[mt][ks] = *(const bf16x8*)(pH + arow + ks * 32);
      am[mt][ks] = *(const bf16x8*)(pM + arow + ks * 32);
      al[mt][ks] = *(const bf16x8*)(pL + arow + ks * 32);
    }
  }
  float bd[2][4]; int bk[2][4];
#pragma unroll
  for (int mt = 0; mt < 2; ++mt)
#pragma unroll
    for (int r = 0; r < 4; ++r) { bd[mt][r] = FLT_MAX; bk[mt][r] = 0; }
  for (int kt = z * 16; kt < z * 16 + 16; ++kt) {
    const unsigned short* bb = eB + (size_t)kt * 12288 + lane * 8;
    f32x4 acc[2][4] = {};
#pragma unroll
    for (int ks = 0; ks < 2; ++ks)
#pragma unroll
      for (int nt = 0; nt < 4; ++nt) {
        const unsigned short* bp = bb + ((ks * 4 + nt) * 3) * 512;
        bf16x8 bh = *(const bf16x8*)(bp);
        bf16x8 bm = *(const bf16x8*)(bp + 512);
        bf16x8 bl = *(const bf16x8*)(bp + 1024);
#pragma unroll
        for (int mt = 0; mt < 2; ++mt) {
          acc[mt][nt] = MFMA16(am[mt][ks], bm, acc[mt][nt]);
          acc[mt][nt] = MFMA16(ah[mt][ks], bl, acc[mt][nt]);
          acc[mt][nt] = MFMA16(al[mt][ks], bh, acc[mt][nt]);
          acc[mt][nt] = MFMA16(ah[mt][ks], bm, acc[mt][nt]);
          acc[mt][nt] = MFMA16(am[mt][ks], bh, acc[mt][nt]);
          acc[mt][nt] = MFMA16(ah[mt][ks], bh, acc[mt][nt]);
        }
      }
    int cb = kt * 64;
#pragma unroll
    for (int nt = 0; nt < 4; ++nt) {
      int code = cb + nt * 16 + l15;
      float nv = n2[code];
#pragma unroll
      for (int mt = 0; mt < 2; ++mt)
#pragma unroll
        for (int r = 0; r < 4; ++r) {
          float d = fmaf(-2.f, acc[mt][nt][r], nv);
          if (d < bd[mt][r]) { bd[mt][r] = d; bk[mt][r] = code; }
        }
    }
  }
#pragma unroll
  for (int mt = 0; mt < 2; ++mt)
#pragma unroll
    for (int r = 0; r < 4; ++r)
#pragma unroll
      for (int s = 1; s < 16; s <<= 1) {
        float od = __shfl_xor(bd[mt][r], s);
        int ok = __shfl_xor(bk[mt][r], s);
        if (od < bd[mt][r] || (od == bd[mt][r] && ok < bk[mt][r])) {
          bd[mt][r] = od; bk[mt][r] = ok;
        }
      }
  if (l15 == 0) {
#pragma unroll
    for (int mt = 0; mt < 2; ++mt)
#pragma unroll
      for (int r = 0; r < 4; ++r) {
        pbd[(size_t)z * 8192 + m0 + mt * 16 + quad * 4 + r] = bd[mt][r];
        pbk[(size_t)z * 8192 + m0 + mt * 16 + quad * 4 + r] = bk[mt][r];
      }
  }
}

// fused: reduce 8 z-groups per row (lex (d,k)) + gather -> 2-plane collected.
__global__ __launch_bounds__(256) void k_vqgather(const float* __restrict__ pbd,
                                                  const int* __restrict__ pbk,
                                                  const float* __restrict__ embeds,
                                                  unsigned short* __restrict__ cH,
                                                  unsigned short* __restrict__ cM) {
  int idx = blockIdx.x * 256 + threadIdx.x;   // 524288, 2048 blocks
  int m = idx >> 6;
  float bd = pbd[m]; int bk = pbk[m];
#pragma unroll
  for (int z = 1; z < 8; ++z) {
    float d = pbd[(size_t)z * 8192 + m]; int k = pbk[(size_t)z * 8192 + m];
    if (d < bd || (d == bd && k < bk)) { bd = d; bk = k; }
  }
  float v = embeds[(size_t)bk * 64 + (idx & 63)];
  unsigned short hb = f2bf(v);
  cH[idx] = hb;
  cM[idx] = f2bf(v - bf2f(hb));
}

// ---------------- dec3: d2buf(permuted) -> out(256,64,64), +bias, no relu ----
__global__ __launch_bounds__(256) void k_dec3(const float* __restrict__ d2buf,
                                              const float* __restrict__ w3,
                                              const float* __restrict__ b3,
                                              float* __restrict__ out) {
  __shared__ float sx[16 * 129];
  __shared__ float wT[128 * 16];
  int b = blockIdx.x >> 4;          // 4096 blocks: (b, y_in)
  int y = blockIdx.x & 15;
  int t = threadIdx.x;
#pragma unroll
  for (int j = 0; j < 8; ++j) {
    int idx = t + j * 256;          // 2048
    int xx = idx >> 7, c = idx & 127;
    size_t m2 = ((size_t)b * 4 + (y >> 2)) * 4 + (xx >> 2);
    sx[xx * 129 + c] = d2buf[m2 * 2048 + ((y & 3) * 4 + (xx & 3)) * 128 + c];
  }
#pragma unroll
  for (int j = 0; j < 8; ++j) {
    int idx = t + j * 256;
    int c = idx >> 4, ru = idx & 15;
    int R = ru >> 2, U = ru & 3;
    wT[c * 16 + ru] = w3[((3 - R) * 4 + (3 - U)) * 128 + c];
  }
  __syncthreads();
  int xx = t >> 4, ru = t & 15;
  float a0 = 0, a1 = 0, a2 = 0, a3 = 0;
#pragma unroll 8
  for (int c = 0; c < 128; c += 4) {
    a0 = fmaf(sx[xx * 129 + c + 0], wT[(c + 0) * 16 + ru], a0);
    a1 = fmaf(sx[xx * 129 + c + 1], wT[(c + 1) * 16 + ru], a1);
    a2 = fmaf(sx[xx * 129 + c + 2], wT[(c + 2) * 16 + ru], a2);
    a3 = fmaf(sx[xx * 129 + c + 3], wT[(c + 3) * 16 + ru], a3);
  }
  float acc = (a0 + a1) + (a2 + a3) + b3[0];
  int R = ru >> 2, U = ru & 3;
  out[((size_t)b * 64 + 4 * y + R) * 64 + 4 * xx + U] = acc;
}

// =====================================================================
extern "C" void kernel_launch(void* const* d_in, const int* in_sizes, int n_in,
                              void* d_out, int out_size, void* d_ws, size_t ws_size,
                              hipStream_t stream) {
  const float* x        = (const float*)d_in[0];
  const float* enc_w1   = (const float*)d_in[1];
  const float* enc_b1   = (const float*)d_in[2];
  const float* enc_w2   = (const float*)d_in[3];
  const float* enc_b2   = (const float*)d_in[4];
  const float* enc_w3   = (const float*)d_in[5];
  const float* enc_b3   = (const float*)d_in[6];
  const float* fc_w     = (const float*)d_in[7];
  const float* fc_b     = (const float*)d_in[8];
  const float* ffc_w    = (const float*)d_in[9];
  const float* ffc_b    = (const float*)d_in[10];
  const float* embeds   = (const float*)d_in[11];
  const float* dec_fc_w = (const float*)d_in[12];
  const float* dec_fc_b = (const float*)d_in[13];
  const float* dec_w1   = (const float*)d_in[14];
  const float* dec_b1   = (const float*)d_in[15];
  const float* dec_w2   = (const float*)d_in[16];
  const float* dec_b2   = (const float*)d_in[17];
  const float* dec_w3   = (const float*)d_in[18];
  const float* dec_b3   = (const float*)d_in[19];
  float* outp = (float*)d_out;

  char* ws = (char*)d_ws;
  size_t off = 0;
  auto alloc = [&](size_t bytes) { size_t r = off; off = (off + bytes + 255) & ~(size_t)255; return r; };

  // ---- Region A (57.15 MB): phase1 h1p splits; phase2 decoder/partials ----
  size_t RA = alloc(57147392);
  unsigned short* h1pH = (unsigned short*)(ws + RA);
  unsigned short* h1pM = (unsigned short*)(ws + RA + 18939904);
  unsigned short* h1pL = (unsigned short*)(ws + RA + 37879808);
  float* d2buf            = (float*)(ws + RA);                    // 33.55 MB
  float* partials         = (float*)(ws + RA + 33554432);         // <=16.78 MB
  unsigned short* Bp_d1   = (unsigned short*)(ws + RA + 41943040);// 8.39 MB
  unsigned short* d1H     = (unsigned short*)(ws + RA + 50331648);
  unsigned short* d1M     = (unsigned short*)(ws + RA + 52428800);
  unsigned short* hdH     = (unsigned short*)(ws + RA + 54525952);
  unsigned short* hdM     = (unsigned short*)(ws + RA + 54788096);
  unsigned short* cH      = (unsigned short*)(ws + RA + 55050240);
  unsigned short* cM      = (unsigned short*)(ws + RA + 56098816);

  // ---- Region B (31.85 MB): phase1 h2p splits; phase2 Bp_fc/pred ----
  size_t RB = alloc(31850496);
  unsigned short* h2pH = (unsigned short*)(ws + RB);
  unsigned short* h2pM = (unsigned short*)(ws + RB + 10616832);
  unsigned short* h2pL = (unsigned short*)(ws + RB + 21233664);
  unsigned short* Bp_fc = (unsigned short*)(ws + RB);             // 25.17 MB
  unsigned short* pH    = (unsigned short*)(ws + RB + 28311552);
  unsigned short* pM    = (unsigned short*)(ws + RB + 29360128);
  unsigned short* pL    = (unsigned short*)(ws + RB + 30408704);

  // ---- Region C (12.58 MB): phase1 h3 splits; phase2 Bp_ffc/hfc ----
  size_t RC = alloc(12582912);
  unsigned short* h3H = (unsigned short*)(ws + RC);
  unsigned short* h3M = (unsigned short*)(ws + RC + 4194304);
  unsigned short* h3L = (unsigned short*)(ws + RC + 8388608);
  unsigned short* Bp_ffc = (unsigned short*)(ws + RC);            // 6.29 MB (after fc)
  unsigned short* hfcH   = (unsigned short*)(ws + RC + 6291456);
  unsigned short* hfcM   = (unsigned short*)(ws + RC + 6553600);
  unsigned short* hfcL   = (unsigned short*)(ws + RC + 6815744);

  // ---- dedicated (lifetime spans whole run) ----
  unsigned short* eB     = (unsigned short*)(ws + alloc(3145728));
  unsigned short* Bp_dfc = (unsigned short*)(ws + alloc(4194304));
  unsigned short* Bp_d2  = (unsigned short*)(ws + alloc(2097152));
  float* n2buf   = (float*)(ws + alloc(32768));
  float* pbd     = (float*)(ws + alloc(262144));
  int*   pbk     = (int*)  (ws + alloc(262144));
  unsigned short* Wp2H = (unsigned short*)(ws + alloc(196608));
  unsigned short* Wp2M = Wp2H + 32768;
  unsigned short* Wp2L = Wp2M + 32768;
  unsigned short* Wp3H = (unsigned short*)(ws + alloc(786432));
  unsigned short* Wp3M = Wp3H + 131072;
  unsigned short* Wp3L = Wp3M + 131072;
  (void)ws_size; (void)in_sizes; (void)n_in; (void)out_size;

  // all input-only prep in one launch
  k_prep_early<<<PB7, 256, 0, stream>>>(
      enc_w2, enc_w3, embeds, dec_fc_w, dec_w2, h1pH, h2pH,
      Wp2H, Wp2M, Wp2L, Wp3H, Wp3M, Wp3L, eB, n2buf, Bp_dfc, Bp_d2);

  k_conv1<<<8192, 256, 0, stream>>>(x, enc_w1, enc_b1, h1pH, h1pM, h1pL);
  k_conv2s<<<256, 1024, 0, stream>>>(h1pH, h1pM, h1pL, Wp2H, Wp2M, Wp2L,
                                     enc_b2, h2pH, h2pM, h2pL);
  k_conv3m<<<dim3(512, 2), 256, 0, stream>>>(h2pH, h2pM, h2pL,
                                             Wp3H, Wp3M, Wp3L, partials);
  // sumrelu(conv3) + bprep fc in one launch
  k_prep_fc<<<FB1, 256, 0, stream>>>(partials, enc_b3, h3H, h3M, h3L,
                                     fc_w, Bp_fc);

  // fc: (256x512) = h3(256x8192) @ fc_w, NP=3, S=16
  k_mgemm<3, 4><<<dim3(4, 8, 16), 256, 0, stream>>>(
      h3H, h3M, h3L, Bp_fc, partials, fc_b, 256, 512, 8192, 511);
  // bprep ffc + bprep_ct dec_w1 in one launch
  k_prep_w2<<<WB1, 256, 0, stream>>>(ffc_w, Bp_ffc, dec_w1, Bp_d1);
  k_sumrelu3<3><<<512, 256, 0, stream>>>(partials, fc_b, hfcH, hfcM, hfcL,
                                         131072, 511, 16);
  // ffc: (256x2048), NP=3, S=4 -> pred splits
  k_mgemm<3, 4><<<dim3(4, 32, 4), 256, 0, stream>>>(
      hfcH, hfcM, hfcL, Bp_ffc, partials, ffc_b, 256, 2048, 512, 2047);
  k_sumrelu3<3><<<2048, 256, 0, stream>>>(partials, ffc_b, pH, pM, pL,
                                          524288, 2047, 4);

  // VQ
  k_vqmfma3<<<dim3(64, 8), 256, 0, stream>>>(pH, pM, pL, eB, n2buf, pbd, pbk);
  k_vqgather<<<2048, 256, 0, stream>>>(pbd, pbk, embeds, cH, cM);

  // dec_fc: (256x512), NP=2, S=16
  k_mgemm<2, 4><<<dim3(4, 8, 16), 256, 0, stream>>>(
      cH, cM, nullptr, Bp_dfc, partials, dec_fc_b, 256, 512, 2048, 511);
  k_sumrelu3<2><<<512, 256, 0, stream>>>(partials, dec_fc_b, hdH, hdM, nullptr,
                                         131072, 511, 16);

  // dec1: (256x4096), NP=2, S=2
  k_mgemm<2, 4><<<dim3(4, 64, 2), 256, 0, stream>>>(
      hdH, hdM, nullptr, Bp_d1, partials, dec_b1, 256, 4096, 512, 255);
  k_sumrelu3<2><<<4096, 256, 0, stream>>>(partials, dec_b1, d1H, d1M, nullptr,
                                          1048576, 255, 2);

  // dec2: (4096x2048), NP=2, S=1 -> fp32 d2buf (+bias+relu)
  k_mgemm<2, 8><<<dim3(64, 16, 1), 256, 0, stream>>>(
      d1H, d1M, nullptr, Bp_d2, d2buf, dec_b2, 4096, 2048, 256, 127);

  // dec3 -> final output (no relu)
  k_dec3<<<4096, 256, 0, stream>>>(d2buf, dec_w3, dec_b3, outp);
}

// Round 3
// 431.842 us; speedup vs baseline: 1.0719x; 1.0293x over previous
//
#include <hip/hip_runtime.h>
#include <cfloat>

// =====================================================================
// VQ-VAE forward.
// R12: identical to R11 (bench infra failed twice, no kernel evidence;
// re-running the A/B). R11 = k_conv3m -> k_conv3s: LDS-weight-staging
// recipe from R10 plus mt=2 (32 px/wave) so each B fragment feeds 2x
// MFMAs. R10 counters: conv3m 54us, MfmaUtil 18%, HBM 8.7% --
// issue-bound on 786 MB of L2 re-reads of the 786 KB Wp3 tensor.
// 512-thr blocks (8 waves = 4 mgroups x 2 ch), grid (128,2); per-s
// 48 KB weight slice double-buffered in 96 KB LDS (reg-prefetch s+1
// during compute, one barrier/s). MFMA floor 12.4us; predict ~16-20us.
// Bit-identical MFMA order -> same numerics.
//
// conv_transpose (transpose_kernel=False) => flipped kernel:
//   out[4i+r, 4j+u, o] = sum_c in[i,j,c] * w[3-r, 3-u, c, o]
// Encoder convs: SAME pad = (1,1) -> padded split inputs.
// Precision: NP=3 split (6 MFMA products) ~= fp32 (2^-25 rel) for
// everything feeding the argmin; NP=2 (3 products, ~1e-5 rel) for the
// decoder (threshold 2.5e-4).
// =====================================================================

typedef short bf16x8 __attribute__((ext_vector_type(8)));
typedef float f32x4 __attribute__((ext_vector_type(4)));
#define MFMA16(a, b, c) __builtin_amdgcn_mfma_f32_16x16x32_bf16(a, b, c, 0, 0, 0)

__device__ inline unsigned short f2bf(float x) {  // RNE, inputs finite
  unsigned u = __float_as_uint(x);
  u += 0x7fffu + ((u >> 16) & 1u);
  return (unsigned short)(u >> 16);
}
__device__ inline float bf2f(unsigned short h) {
  return __uint_as_float(((unsigned)h) << 16);
}
__device__ inline void split3v(float v, unsigned short& hb, unsigned short& mb,
                               unsigned short& lb) {
  hb = f2bf(v);
  float r1 = v - bf2f(hb);
  mb = f2bf(r1);
  lb = f2bf(r1 - bf2f(mb));
}

// ---------------- fused input-only prep (one launch) ----------------
// segments: zborder h1p | zborder h2p | wprep2 | wprep3 | eprep | norm2 |
// bprep dec_fc (NP2) | bprep_ct dec_w2 (NP2)
#define PB0 12672
#define PB1 (PB0 + 13056)
#define PB2 (PB1 + 128)
#define PB3 (PB2 + 512)
#define PB4 (PB3 + 2048)
#define PB5 (PB4 + 32)
#define PB6 (PB5 + 4096)
#define PB7 (PB6 + 2048)
__global__ __launch_bounds__(256) void k_prep_early(
    const float* __restrict__ enc_w2, const float* __restrict__ enc_w3,
    const float* __restrict__ embeds, const float* __restrict__ dec_fc_w,
    const float* __restrict__ dec_w2, unsigned short* __restrict__ h1base,
    unsigned short* __restrict__ h2base, unsigned short* __restrict__ Wp2H,
    unsigned short* __restrict__ Wp2M, unsigned short* __restrict__ Wp2L,
    unsigned short* __restrict__ Wp3H, unsigned short* __restrict__ Wp3M,
    unsigned short* __restrict__ Wp3L, unsigned short* __restrict__ eB,
    float* __restrict__ n2, unsigned short* __restrict__ Bp_dfc,
    unsigned short* __restrict__ Bp_d2) {
  int blk = blockIdx.x;
  int t = threadIdx.x;
  if (blk < PB0) {                       // zborder h1p (W=34, C=32)
    int li = blk * 256 + t;
    int bc = li & 8191;
    int rest = li >> 13;                 // i + 132*plane
    int i = rest % 132, plane = rest / 132;
    int b = bc >> 5, c = bc & 31;
    int row, col;
    if (i < 34) { row = 0; col = i; }
    else if (i < 68) { row = 33; col = i - 34; }
    else { int j = i - 68; row = 1 + (j >> 1); col = (j & 1) ? 33 : 0; }
    h1base[(size_t)plane * 9469952 + ((size_t)(b * 34 + row) * 34 + col) * 32 + c] = 0;
  } else if (blk < PB1) {                // zborder h2p (W=18, C=64)
    int li = (blk - PB0) * 256 + t;
    int bc = li & 16383;
    int rest = li >> 14;
    int i = rest % 68, plane = rest / 68;
    int b = bc >> 6, c = bc & 63;
    int row, col;
    if (i < 18) { row = 0; col = i; }
    else if (i < 36) { row = 17; col = i - 18; }
    else { int j = i - 36; row = 1 + (j >> 1); col = (j & 1) ? 17 : 0; }
    h2base[(size_t)plane * 5308416 + ((size_t)(b * 18 + row) * 18 + col) * 64 + c] = 0;
  } else if (blk < PB2) {                // wprep2
    int idx = (blk - PB1) * 256 + t;     // 32768
    int j = idx & 7, lane = (idx >> 3) & 63, nt = (idx >> 9) & 3, s = idx >> 11;
    int ci = ((lane >> 4) << 3) + j, co = (nt << 4) + (lane & 15);
    unsigned short hb, mb, lb;
    split3v(enc_w2[(s * 32 + ci) * 64 + co], hb, mb, lb);
    Wp2H[idx] = hb; Wp2M[idx] = mb; Wp2L[idx] = lb;
  } else if (blk < PB3) {                // wprep3
    int idx = (blk - PB2) * 256 + t;     // 131072
    int j = idx & 7, lane = (idx >> 3) & 63, ks = (idx >> 9) & 1;
    int nt = (idx >> 10) & 3, ch = (idx >> 12) & 1, s = idx >> 13;
    int ci = ks * 32 + ((lane >> 4) << 3) + j;
    int co = ch * 64 + (nt << 4) + (lane & 15);
    unsigned short hb, mb, lb;
    split3v(enc_w3[(s * 64 + ci) * 128 + co], hb, mb, lb);
    Wp3H[idx] = hb; Wp3M[idx] = mb; Wp3L[idx] = lb;
  } else if (blk < PB4) {                // eprep (one read -> 3 writes)
    int idx = (blk - PB3) * 256 + t;     // 524,288
    int j = idx & 7, lane = (idx >> 3) & 63;
    int f = idx >> 9;                    // (kt*2+ks)*4+nt
    int nt = f & 3, ks = (f >> 2) & 1, kt = f >> 3;
    int code = kt * 64 + nt * 16 + (lane & 15);
    int k = ks * 32 + ((lane >> 4) << 3) + j;
    unsigned short hb, mb, lb;
    split3v(embeds[(size_t)code * 64 + k], hb, mb, lb);
    size_t base = (size_t)f * 1536 + lane * 8 + j;
    eB[base] = hb; eB[base + 512] = mb; eB[base + 1024] = lb;
  } else if (blk < PB5) {                // norm2
    int k = (blk - PB4) * 256 + t;       // 8192
    const float4* p = (const float4*)(embeds + (size_t)k * 64);
    float s0 = 0, s1 = 0, s2 = 0, s3 = 0;
#pragma unroll
    for (int j = 0; j < 16; ++j) {
      float4 v = p[j];
      s0 = fmaf(v.x, v.x, s0); s1 = fmaf(v.y, v.y, s1);
      s2 = fmaf(v.z, v.z, s2); s3 = fmaf(v.w, v.w, s3);
    }
    n2[k] = (s0 + s1) + (s2 + s3);
  } else if (blk < PB6) {                // bprep dec_fc NP=2 (K=2048,N=512)
    int idx = (blk - PB5) * 256 + t;     // 1,048,576
    int j = idx & 7, lane = (idx >> 3) & 63;
    int f = idx >> 9;
    int ntg = f & 31;                    // NT=32
    int kt = f >> 5;                     // KT=64
    int k = kt * 32 + ((lane >> 4) << 3) + j;
    int n = ntg * 16 + (lane & 15);
    unsigned short hb, mb, lb;
    split3v(dec_fc_w[(size_t)k * 512 + n], hb, mb, lb);
    Bp_dfc[idx] = hb; Bp_dfc[idx + 1048576] = mb;
  } else if (blk < PB7) {                // bprep_ct dec_w2 NP=2 (K=256,N=2048,CO=128)
    int idx = (blk - PB6) * 256 + t;     // 524,288
    int j = idx & 7, lane = (idx >> 3) & 63;
    int f = idx >> 9;
    int ntg = f & 127;                   // NT=128
    int kt = f >> 7;                     // KT=8
    int k = kt * 32 + ((lane >> 4) << 3) + j;
    int n = ntg * 16 + (lane & 15);
    int o = n & 127, ru = n >> 7;
    int r = ru >> 2, u = ru & 3;
    int sf = (3 - r) * 4 + (3 - u);
    unsigned short hb, mb, lb;
    split3v(dec_w2[(((size_t)sf * 256 + k) << 7) + o], hb, mb, lb);
    Bp_d2[idx] = hb; Bp_d2[idx + 524288] = mb;
  }
}

// ---------------- conv1: x(256,64,64,1) -> h1p split padded (256,34,34,32) ----
__global__ __launch_bounds__(256) void k_conv1(const float* __restrict__ x,
                                               const float* __restrict__ w,
                                               const float* __restrict__ bias,
                                               unsigned short* __restrict__ oH,
                                               unsigned short* __restrict__ oM,
                                               unsigned short* __restrict__ oL) {
  int b = blockIdx.x >> 5;          // 8192 blocks: (b, y)
  int y = blockIdx.x & 31;
  int t = threadIdx.x;
  int c = t & 31;
  int xg = t >> 5;                  // 0..7, 4 x-positions each
  float acc[4] = {0.f, 0.f, 0.f, 0.f};
  for (int dy = 0; dy < 4; ++dy) {
    int iy = 2 * y + dy - 1;
    if (iy < 0 || iy >= 64) continue;
    const float* xrow = x + ((size_t)b * 64 + iy) * 64;
    for (int dx = 0; dx < 4; ++dx) {
      float wv = w[(dy * 4 + dx) * 32 + c];
#pragma unroll
      for (int i = 0; i < 4; ++i) {
        int ix = 8 * xg + 2 * i + dx - 1;
        float v = (ix >= 0 && ix < 64) ? xrow[ix] : 0.f;
        acc[i] = fmaf(v, wv, acc[i]);
      }
    }
  }
  float bv = bias[c];
#pragma unroll
  for (int i = 0; i < 4; ++i) {
    float v = acc[i] + bv;
    v = v > 0.f ? v : 0.f;
    unsigned short hb, mb, lb;
    split3v(v, hb, mb, lb);
    size_t o = ((size_t)(b * 34 + y + 1) * 34 + (4 * xg + i + 1)) * 32 + c;
    oH[o] = hb; oM[o] = mb; oL[o] = lb;
  }
}

// ---------------- conv2 MFMA, LDS-staged weights ----------------
// 1024-thread blocks (16 waves), 256 blocks = 1 block/CU, 4 waves/SIMD.
// Bs holds one s-half of the NP=3 split weights: 3 planes x 8 s x 4 nt
// x 64 lanes x 8 shorts = 49152 shorts = 96 KB.
__global__ __launch_bounds__(1024, 4) void k_conv2s(
    const unsigned short* __restrict__ aH, const unsigned short* __restrict__ aM,
    const unsigned short* __restrict__ aL, const unsigned short* __restrict__ wH,
    const unsigned short* __restrict__ wM, const unsigned short* __restrict__ wL,
    const float* __restrict__ bias, unsigned short* __restrict__ oH,
    unsigned short* __restrict__ oM, unsigned short* __restrict__ oL) {
  __shared__ unsigned short Bs[49152];      // 96 KB
  int t = threadIdx.x;
  int wave = t >> 6, lane = t & 63;
  int l15 = lane & 15, quad = lane >> 4;
  int m0 = blockIdx.x * 256 + wave * 16;    // 256 blocks x 256 px
  int p = m0 + l15;
  int b = p >> 8, y = (p >> 4) & 15, x = p & 15;
  f32x4 acc[4] = {};
#pragma unroll
  for (int hf = 0; hf < 2; ++hf) {
    if (hf) __syncthreads();                // all waves done reading half 0
    // stage half hf: per plane 16384 shorts (= s in [8hf, 8hf+8))
    {
      const unsigned short* s0 = wH + hf * 16384;
      const unsigned short* s1 = wM + hf * 16384;
      const unsigned short* s2 = wL + hf * 16384;
#pragma unroll
      for (int i = 0; i < 2; ++i) {
        int o8 = (i * 1024 + t) * 8;
        *(bf16x8*)(Bs + o8)         = *(const bf16x8*)(s0 + o8);
        *(bf16x8*)(Bs + 16384 + o8) = *(const bf16x8*)(s1 + o8);
        *(bf16x8*)(Bs + 32768 + o8) = *(const bf16x8*)(s2 + o8);
      }
    }
    __syncthreads();
#pragma unroll 4
    for (int sl = 0; sl < 8; ++sl) {
      int s = hf * 8 + sl;
      int dy = s >> 2, dx = s & 3;
      size_t aoff = ((size_t)(b * 34 + 2 * y + dy) * 34 + (2 * x + dx)) * 32 + quad * 8;
      bf16x8 ah = *(const bf16x8*)(aH + aoff);
      bf16x8 am = *(const bf16x8*)(aM + aoff);
      bf16x8 al = *(const bf16x8*)(aL + aoff);
#pragma unroll
      for (int nt = 0; nt < 4; ++nt) {
        const unsigned short* bp = Bs + ((sl * 4 + nt) * 64 + lane) * 8;
        bf16x8 bh = *(const bf16x8*)(bp);
        bf16x8 bm = *(const bf16x8*)(bp + 16384);
        bf16x8 bl = *(const bf16x8*)(bp + 32768);
        acc[nt] = MFMA16(am, bm, acc[nt]);
        acc[nt] = MFMA16(ah, bl, acc[nt]);
        acc[nt] = MFMA16(al, bh, acc[nt]);
        acc[nt] = MFMA16(ah, bm, acc[nt]);
        acc[nt] = MFMA16(am, bh, acc[nt]);
        acc[nt] = MFMA16(ah, bh, acc[nt]);
      }
    }
  }
#pragma unroll
  for (int r = 0; r < 4; ++r) {
    int pp = m0 + quad * 4 + r;
    int b2 = pp >> 8, yo = (pp >> 4) & 15, xo = pp & 15;
    size_t obase = ((size_t)(b2 * 18 + yo + 1) * 18 + (xo + 1)) * 64;
#pragma unroll
    for (int nt = 0; nt < 4; ++nt) {
      int co = nt * 16 + l15;
      float v = acc[nt][r] + bias[co];
      v = v > 0.f ? v : 0.f;
      unsigned short hb, mb, lb;
      split3v(v, hb, mb, lb);
      oH[obase + co] = hb; oM[obase + co] = mb; oL[obase + co] = lb;
    }
  }
}

// ---------------- conv3 MFMA, LDS-staged weights, mt=2 ----------------
// 512-thread blocks (8 waves = 4 mgroups x 2 ch), grid (128, 2): block =
// 128 px x 128 co at one z-half (8 s-steps). Per-s weight slice is
// contiguous in Wp3 (8192 shorts/plane = 48 KB for 3 planes); double-
// buffered in 96 KB LDS, reg-prefetch of s+1 overlapped with compute,
// one barrier per s. Wave = 32 px x 64 co (mt=2) so each B fragment
// feeds 2x MFMAs. Output: fp32 partials [z][16384][128] (same as R10).
__global__ __launch_bounds__(512, 2) void k_conv3s(
    const unsigned short* __restrict__ aH, const unsigned short* __restrict__ aM,
    const unsigned short* __restrict__ aL, const unsigned short* __restrict__ wH,
    const unsigned short* __restrict__ wM, const unsigned short* __restrict__ wL,
    float* __restrict__ part) {
  __shared__ unsigned short Bs[2][24576];   // [dbuf][plane*8192 + frag] 96 KB
  int t = threadIdx.x;
  int wave = t >> 6, lane = t & 63;
  int l15 = lane & 15, quad = lane >> 4;
  int ch = wave & 1, mg = wave >> 1;
  int m0 = blockIdx.x * 128 + mg * 32;
  int z = blockIdx.y;
  f32x4 acc[2][4] = {};
  {  // stage s = z*8 into buf 0
    const unsigned short* srcH = wH + (size_t)(z * 8) * 8192;
    const unsigned short* srcM = wM + (size_t)(z * 8) * 8192;
    const unsigned short* srcL = wL + (size_t)(z * 8) * 8192;
#pragma unroll
    for (int i = 0; i < 2; ++i) {
      int o8 = (i * 512 + t) * 8;
      *(bf16x8*)(&Bs[0][o8])         = *(const bf16x8*)(srcH + o8);
      *(bf16x8*)(&Bs[0][8192 + o8])  = *(const bf16x8*)(srcM + o8);
      *(bf16x8*)(&Bs[0][16384 + o8]) = *(const bf16x8*)(srcL + o8);
    }
  }
  __syncthreads();
#pragma unroll 2
  for (int si = 0; si < 8; ++si) {
    int s = z * 8 + si;
    int cur = si & 1, nxt = cur ^ 1;
    bf16x8 stg[6];
    if (si < 7) {                           // prefetch s+1 into regs
      const unsigned short* srcH = wH + (size_t)(s + 1) * 8192;
      const unsigned short* srcM = wM + (size_t)(s + 1) * 8192;
      const unsigned short* srcL = wL + (size_t)(s + 1) * 8192;
#pragma unroll
      for (int i = 0; i < 2; ++i) {
        int o8 = (i * 512 + t) * 8;
        stg[i]     = *(const bf16x8*)(srcH + o8);
        stg[2 + i] = *(const bf16x8*)(srcM + o8);
        stg[4 + i] = *(const bf16x8*)(srcL + o8);
      }
    }
    int dy = s >> 2, dx = s & 3;
    bf16x8 ah[2][2], am[2][2], al[2][2];    // [mt][ks]
#pragma unroll
    for (int mt = 0; mt < 2; ++mt) {
      int p = m0 + mt * 16 + l15;
      int b = p >> 6, y = (p >> 3) & 7, x = p & 7;
      size_t base = ((size_t)(b * 18 + 2 * y + dy) * 18 + (2 * x + dx)) * 64 + quad * 8;
#pragma unroll
      for (int ks = 0; ks < 2; ++ks) {
        ah[mt][ks] = *(const bf16x8*)(aH + base + ks * 32);
        am[mt][ks] = *(const bf16x8*)(aM + base + ks * 32);
        al[mt][ks] = *(const bf16x8*)(aL + base + ks * 32);
      }
    }
#pragma unroll
    for (int nt = 0; nt < 4; ++nt)
#pragma unroll
      for (int ks = 0; ks < 2; ++ks) {
        const unsigned short* bp =
            &Bs[cur][((ch * 4 + nt) * 2 + ks) * 512 + lane * 8];
        bf16x8 bh = *(const bf16x8*)(bp);
        bf16x8 bm = *(const bf16x8*)(bp + 8192);
        bf16x8 bl = *(const bf16x8*)(bp + 16384);
#pragma unroll
        for (int mt = 0; mt < 2; ++mt) {
          acc[mt][nt] = MFMA16(am[mt][ks], bm, acc[mt][nt]);
          acc[mt][nt] = MFMA16(ah[mt][ks], bl, acc[mt][nt]);
          acc[mt][nt] = MFMA16(al[mt][ks], bh, acc[mt][nt]);
          acc[mt][nt] = MFMA16(ah[mt][ks], bm, acc[mt][nt]);
          acc[mt][nt] = MFMA16(am[mt][ks], bh, acc[mt][nt]);
          acc[mt][nt] = MFMA16(ah[mt][ks], bh, acc[mt][nt]);
        }
      }
    if (si < 7) {                           // write prefetched s+1
#pragma unroll
      for (int i = 0; i < 2; ++i) {
        int o8 = (i * 512 + t) * 8;
        *(bf16x8*)(&Bs[nxt][o8])         = stg[i];
        *(bf16x8*)(&Bs[nxt][8192 + o8])  = stg[2 + i];
        *(bf16x8*)(&Bs[nxt][16384 + o8]) = stg[4 + i];
      }
    }
    __syncthreads();
  }
  float* Cp = part + (size_t)z * 2097152;
#pragma unroll
  for (int mt = 0; mt < 2; ++mt)
#pragma unroll
    for (int nt = 0; nt < 4; ++nt) {
      int co = ch * 64 + nt * 16 + l15;
#pragma unroll
      for (int r = 0; r < 4; ++r) {
        int pp = m0 + mt * 16 + quad * 4 + r;
        Cp[(size_t)pp * 128 + co] = acc[mt][nt][r];
      }
    }
}

// ---------------- fused: sumrelu(conv3) + bprep fc (NP=3) ----------------
#define FB0 8192
#define FB1 (FB0 + 16384)
__global__ __launch_bounds__(256) void k_prep_fc(
    const float* __restrict__ part, const float* __restrict__ enc_b3,
    unsigned short* __restrict__ h3H, unsigned short* __restrict__ h3M,
    unsigned short* __restrict__ h3L, const float* __restrict__ fc_w,
    unsigned short* __restrict__ Bp_fc) {
  int blk = blockIdx.x;
  int t = threadIdx.x;
  if (blk < FB0) {                       // sumrelu conv3: MN=2097152, S=2
    int idx = blk * 256 + t;
    float s = part[idx] + part[2097152 + idx] + enc_b3[idx & 127];
    s = s > 0.f ? s : 0.f;
    unsigned short hb, mb, lb;
    split3v(s, hb, mb, lb);
    h3H[idx] = hb; h3M[idx] = mb; h3L[idx] = lb;
  } else {                               // bprep fc: K=8192, N=512 (KT=256,NT=32)
    int idx = (blk - FB0) * 256 + t;     // 4,194,304
    int j = idx & 7, lane = (idx >> 3) & 63;
    int f = idx >> 9;
    int ntg = f & 31;
    int kt = f >> 5;
    int k = kt * 32 + ((lane >> 4) << 3) + j;
    int n = ntg * 16 + (lane & 15);
    unsigned short hb, mb, lb;
    split3v(fc_w[(size_t)k * 512 + n], hb, mb, lb);
    Bp_fc[idx] = hb; Bp_fc[idx + 4194304] = mb; Bp_fc[idx + 8388608] = lb;
  }
}

// ---------------- fused: bprep ffc (NP=3) + bprep_ct dec_w1 (NP=2) ----------
#define WB0 4096
#define WB1 (WB0 + 8192)
__global__ __launch_bounds__(256) void k_prep_w2(
    const float* __restrict__ ffc_w, unsigned short* __restrict__ Bp_ffc,
    const float* __restrict__ dec_w1, unsigned short* __restrict__ Bp_d1) {
  int blk = blockIdx.x;
  int t = threadIdx.x;
  if (blk < WB0) {                       // ffc: K=512, N=2048 (KT=16, NT=128)
    int idx = blk * 256 + t;             // 1,048,576
    int j = idx & 7, lane = (idx >> 3) & 63;
    int f = idx >> 9;
    int ntg = f & 127;
    int kt = f >> 7;
    int k = kt * 32 + ((lane >> 4) << 3) + j;
    int n = ntg * 16 + (lane & 15);
    unsigned short hb, mb, lb;
    split3v(ffc_w[(size_t)k * 2048 + n], hb, mb, lb);
    Bp_ffc[idx] = hb; Bp_ffc[idx + 1048576] = mb; Bp_ffc[idx + 2097152] = lb;
  } else {                               // dec_w1 ct: K=512, N=4096, CO=256
    int idx = (blk - WB0) * 256 + t;     // 2,097,152
    int j = idx & 7, lane = (idx >> 3) & 63;
    int f = idx >> 9;
    int ntg = f & 255;                   // NT=256
    int kt = f >> 8;                     // KT=16
    int k = kt * 32 + ((lane >> 4) << 3) + j;
    int n = ntg * 16 + (lane & 15);
    int o = n & 255, ru = n >> 8;
    int r = ru >> 2, u = ru & 3;
    int sf = (3 - r) * 4 + (3 - u);
    unsigned short hb, mb, lb;
    split3v(dec_w1[(((size_t)sf * 512 + k) << 8) + o], hb, mb, lb);
    Bp_d1[idx] = hb; Bp_d1[idx + 2097152] = mb;
  }
}

// ---------------- generic split-bf16 MFMA GEMM ----------------
template <int NP, int NTW>
__global__ __launch_bounds__(256) void k_mgemm(
    const unsigned short* __restrict__ A0, const unsigned short* __restrict__ A1,
    const unsigned short* __restrict__ A2, const unsigned short* __restrict__ Bp,
    float* __restrict__ C, const float* __restrict__ bias,
    int M, int N, int K, int bmask) {
  int S = gridDim.z;
  int Kc = K / S;
  int t = threadIdx.x;
  int wave = t >> 6, lane = t & 63;
  int l15 = lane & 15, quad = lane >> 4;
  int m0 = blockIdx.x * 64 + wave * 16;
  int n0 = blockIdx.y * (16 * NTW);
  int KT = K >> 5, NT = N >> 4;
  int kt0 = (blockIdx.z * Kc) >> 5;
  int ktn = Kc >> 5;
  size_t sstride = (size_t)KT * NT * 512;
  const unsigned short* arow0 = A0 + (size_t)(m0 + l15) * K + quad * 8;
  const unsigned short* arow1 = A1 + (size_t)(m0 + l15) * K + quad * 8;
  const unsigned short* arow2 = nullptr;
  if constexpr (NP == 3) arow2 = A2 + (size_t)(m0 + l15) * K + quad * 8;
  f32x4 acc[NTW] = {};
  for (int kt = kt0; kt < kt0 + ktn; ++kt) {
    bf16x8 ah = *(const bf16x8*)(arow0 + kt * 32);
    bf16x8 am = *(const bf16x8*)(arow1 + kt * 32);
    bf16x8 al;
    if constexpr (NP == 3) al = *(const bf16x8*)(arow2 + kt * 32);
    const unsigned short* bbase =
        Bp + ((size_t)kt * NT + (n0 >> 4)) * 512 + lane * 8;
#pragma unroll
    for (int nt = 0; nt < NTW; ++nt) {
      const unsigned short* bp = bbase + nt * 512;
      bf16x8 bh = *(const bf16x8*)(bp);
      bf16x8 bm = *(const bf16x8*)(bp + sstride);
      if constexpr (NP == 3) {
        bf16x8 bl = *(const bf16x8*)(bp + 2 * sstride);
        acc[nt] = MFMA16(am, bm, acc[nt]);
        acc[nt] = MFMA16(ah, bl, acc[nt]);
        acc[nt] = MFMA16(al, bh, acc[nt]);
        acc[nt] = MFMA16(ah, bm, acc[nt]);
        acc[nt] = MFMA16(am, bh, acc[nt]);
        acc[nt] = MFMA16(ah, bh, acc[nt]);
      } else {
        acc[nt] = MFMA16(ah, bm, acc[nt]);
        acc[nt] = MFMA16(am, bh, acc[nt]);
        acc[nt] = MFMA16(ah, bh, acc[nt]);
      }
    }
  }
  if (S == 1) {
#pragma unroll
    for (int nt = 0; nt < NTW; ++nt) {
      int n = n0 + nt * 16 + l15;
      float bv = bias[n & bmask];
#pragma unroll
      for (int r = 0; r < 4; ++r) {
        int m = m0 + quad * 4 + r;
        float v = acc[nt][r] + bv;
        C[(size_t)m * N + n] = v > 0.f ? v : 0.f;
      }
    }
  } else {
    float* Cp = C + (size_t)blockIdx.z * M * N;
#pragma unroll
    for (int nt = 0; nt < NTW; ++nt) {
      int n = n0 + nt * 16 + l15;
#pragma unroll
      for (int r = 0; r < 4; ++r) {
        int m = m0 + quad * 4 + r;
        Cp[(size_t)m * N + n] = acc[nt][r];
      }
    }
  }
}

// sum k-split partials + bias + relu -> split planes
template <int NPOUT>
__global__ __launch_bounds__(256) void k_sumrelu3(
    const float* __restrict__ part, const float* __restrict__ bias,
    unsigned short* __restrict__ oH, unsigned short* __restrict__ oM,
    unsigned short* __restrict__ oL, int MN, int bmask, int S) {
  int idx = blockIdx.x * 256 + threadIdx.x;
  float s = 0.f;
  for (int z = 0; z < S; ++z) s += part[(size_t)z * MN + idx];
  s += bias[idx & bmask];
  s = s > 0.f ? s : 0.f;
  unsigned short hb = f2bf(s);
  float r1 = s - bf2f(hb);
  unsigned short mb = f2bf(r1);
  oH[idx] = hb; oM[idx] = mb;
  if constexpr (NPOUT == 3) oL[idx] = f2bf(r1 - bf2f(mb));
}

// ---------------- VQ ----------------
// k_vqmfma3: 32 m-rows per wave (2 A-sets), codes streamed as B-frags.
__global__ __launch_bounds__(256) void k_vqmfma3(
    const unsigned short* __restrict__ pH, const unsigned short* __restrict__ pM,
    const unsigned short* __restrict__ pL, const unsigned short* __restrict__ eB,
    const float* __restrict__ n2, float* __restrict__ pbd, int* __restrict__ pbk) {
  int t = threadIdx.x;
  int wave = t >> 6, lane = t & 63;
  int l15 = lane & 15, quad = lane >> 4;
  int m0 = blockIdx.x * 128 + wave * 32;
  int z = blockIdx.y;
  bf16x8 ah[2][2], am[2][2], al[2][2];   // [mt][ks]
#pragma unroll
  for (int mt = 0; mt < 2; ++mt) {
    size_t arow = (size_t)(m0 + mt * 16 + l15) * 64 + quad * 8;
#pragma unroll
    for (int ks = 0; ks < 2; ++ks) {
      ah[mt][ks] = *(const bf16x8*)(pH + arow + ks * 32);
      am[mt][ks] = *(const bf16x8*)(pM + arow + ks * 32);
      al[mt][ks] = *(const bf16x8*)(pL + arow + ks * 32);
    }
  }
  float bd[2][4]; int bk[2][4];
#pragma unroll
  for (int mt = 0; mt < 2; ++mt)
#pragma unroll
    for (int r = 0; r < 4; ++r) { bd[mt][r] = FLT_MAX; bk[mt][r] = 0; }
  for (int kt = z * 16; kt < z * 16 + 16; ++kt) {
    const unsigned short* bb = eB + (size_t)kt * 12288 + lane * 8;
    f32x4 acc[2][4] = {};
#pragma unroll
    for (int ks = 0; ks < 2; ++ks)
#pragma unroll
      for (int nt = 0; nt < 4; ++nt) {
        const unsigned short* bp = bb + ((ks * 4 + nt) * 3) * 512;
        bf16x8 bh = *(const bf16x8*)(bp);
        bf16x8 bm = *(const bf16x8*)(bp + 512);
        bf16x8 bl = *(const bf16x8*)(bp + 1024);
#pragma unroll
        for (int mt = 0; mt < 2; ++mt) {
          acc[mt][nt] = MFMA16(am[mt][ks], bm, acc[mt][nt]);
          acc[mt][nt] = MFMA16(ah[mt][ks], bl, acc[mt][nt]);
          acc[mt][nt] = MFMA16(al[mt][ks], bh, acc[mt][nt]);
          acc[mt][nt] = MFMA16(ah[mt][ks], bm, acc[mt][nt]);
          acc[mt][nt] = MFMA16(am[mt][ks], bh, acc[mt][nt]);
          acc[mt][nt] = MFMA16(ah[mt][ks], bh, acc[mt][nt]);
        }
      }
    int cb = kt * 64;
#pragma unroll
    for (int nt = 0; nt < 4; ++nt) {
      int code = cb + nt * 16 + l15;
      float nv = n2[code];
#pragma unroll
      for (int mt = 0; mt < 2; ++mt)
#pragma unroll
        for (int r = 0; r < 4; ++r) {
          float d = fmaf(-2.f, acc[mt][nt][r], nv);
          if (d < bd[mt][r]) { bd[mt][r] = d; bk[mt][r] = code; }
        }
    }
  }
#pragma unroll
  for (int mt = 0; mt < 2; ++mt)
#pragma unroll
    for (int r = 0; r < 4; ++r)
#pragma unroll
      for (int s = 1; s < 16; s <<= 1) {
        float od = __shfl_xor(bd[mt][r], s);
        int ok = __shfl_xor(bk[mt][r], s);
        if (od < bd[mt][r] || (od == bd[mt][r] && ok < bk[mt][r])) {
          bd[mt][r] = od; bk[mt][r] = ok;
        }
      }
  if (l15 == 0) {
#pragma unroll
    for (int mt = 0; mt < 2; ++mt)
#pragma unroll
      for (int r = 0; r < 4; ++r) {
        pbd[(size_t)z * 8192 + m0 + mt * 16 + quad * 4 + r] = bd[mt][r];
        pbk[(size_t)z * 8192 + m0 + mt * 16 + quad * 4 + r] = bk[mt][r];
      }
  }
}

// fused: reduce 8 z-groups per row (lex (d,k)) + gather -> 2-plane collected.
__global__ __launch_bounds__(256) void k_vqgather(const float* __restrict__ pbd,
                                                  const int* __restrict__ pbk,
                                                  const float* __restrict__ embeds,
                                                  unsigned short* __restrict__ cH,
                                                  unsigned short* __restrict__ cM) {
  int idx = blockIdx.x * 256 + threadIdx.x;   // 524288, 2048 blocks
  int m = idx >> 6;
  float bd = pbd[m]; int bk = pbk[m];
#pragma unroll
  for (int z = 1; z < 8; ++z) {
    float d = pbd[(size_t)z * 8192 + m]; int k = pbk[(size_t)z * 8192 + m];
    if (d < bd || (d == bd && k < bk)) { bd = d; bk = k; }
  }
  float v = embeds[(size_t)bk * 64 + (idx & 63)];
  unsigned short hb = f2bf(v);
  cH[idx] = hb;
  cM[idx] = f2bf(v - bf2f(hb));
}

// ---------------- dec3: d2buf(permuted) -> out(256,64,64), +bias, no relu ----
__global__ __launch_bounds__(256) void k_dec3(const float* __restrict__ d2buf,
                                              const float* __restrict__ w3,
                                              const float* __restrict__ b3,
                                              float* __restrict__ out) {
  __shared__ float sx[16 * 129];
  __shared__ float wT[128 * 16];
  int b = blockIdx.x >> 4;          // 4096 blocks: (b, y_in)
  int y = blockIdx.x & 15;
  int t = threadIdx.x;
#pragma unroll
  for (int j = 0; j < 8; ++j) {
    int idx = t + j * 256;          // 2048
    int xx = idx >> 7, c = idx & 127;
    size_t m2 = ((size_t)b * 4 + (y >> 2)) * 4 + (xx >> 2);
    sx[xx * 129 + c] = d2buf[m2 * 2048 + ((y & 3) * 4 + (xx & 3)) * 128 + c];
  }
#pragma unroll
  for (int j = 0; j < 8; ++j) {
    int idx = t + j * 256;
    int c = idx >> 4, ru = idx & 15;
    int R = ru >> 2, U = ru & 3;
    wT[c * 16 + ru] = w3[((3 - R) * 4 + (3 - U)) * 128 + c];
  }
  __syncthreads();
  int xx = t >> 4, ru = t & 15;
  float a0 = 0, a1 = 0, a2 = 0, a3 = 0;
#pragma unroll 8
  for (int c = 0; c < 128; c += 4) {
    a0 = fmaf(sx[xx * 129 + c + 0], wT[(c + 0) * 16 + ru], a0);
    a1 = fmaf(sx[xx * 129 + c + 1], wT[(c + 1) * 16 + ru], a1);
    a2 = fmaf(sx[xx * 129 + c + 2], wT[(c + 2) * 16 + ru], a2);
    a3 = fmaf(sx[xx * 129 + c + 3], wT[(c + 3) * 16 + ru], a3);
  }
  float acc = (a0 + a1) + (a2 + a3) + b3[0];
  int R = ru >> 2, U = ru & 3;
  out[((size_t)b * 64 + 4 * y + R) * 64 + 4 * xx + U] = acc;
}

// =====================================================================
extern "C" void kernel_launch(void* const* d_in, const int* in_sizes, int n_in,
                              void* d_out, int out_size, void* d_ws, size_t ws_size,
                              hipStream_t stream) {
  const float* x        = (const float*)d_in[0];
  const float* enc_w1   = (const float*)d_in[1];
  const float* enc_b1   = (const float*)d_in[2];
  const float* enc_w2   = (const float*)d_in[3];
  const float* enc_b2   = (const float*)d_in[4];
  const float* enc_w3   = (const float*)d_in[5];
  const float* enc_b3   = (const float*)d_in[6];
  const float* fc_w     = (const float*)d_in[7];
  const float* fc_b     = (const float*)d_in[8];
  const float* ffc_w    = (const float*)d_in[9];
  const float* ffc_b    = (const float*)d_in[10];
  const float* embeds   = (const float*)d_in[11];
  const float* dec_fc_w = (const float*)d_in[12];
  const float* dec_fc_b = (const float*)d_in[13];
  const float* dec_w1   = (const float*)d_in[14];
  const float* dec_b1   = (const float*)d_in[15];
  const float* dec_w2   = (const float*)d_in[16];
  const float* dec_b2   = (const float*)d_in[17];
  const float* dec_w3   = (const float*)d_in[18];
  const float* dec_b3   = (const float*)d_in[19];
  float* outp = (float*)d_out;

  char* ws = (char*)d_ws;
  size_t off = 0;
  auto alloc = [&](size_t bytes) { size_t r = off; off = (off + bytes + 255) & ~(size_t)255; return r; };

  // ---- Region A (57.15 MB): phase1 h1p splits; phase2 decoder/partials ----
  size_t RA = alloc(57147392);
  unsigned short* h1pH = (unsigned short*)(ws + RA);
  unsigned short* h1pM = (unsigned short*)(ws + RA + 18939904);
  unsigned short* h1pL = (unsigned short*)(ws + RA + 37879808);
  float* d2buf            = (float*)(ws + RA);                    // 33.55 MB
  float* partials         = (float*)(ws + RA + 33554432);         // <=16.78 MB
  unsigned short* Bp_d1   = (unsigned short*)(ws + RA + 41943040);// 8.39 MB
  unsigned short* d1H     = (unsigned short*)(ws + RA + 50331648);
  unsigned short* d1M     = (unsigned short*)(ws + RA + 52428800);
  unsigned short* hdH     = (unsigned short*)(ws + RA + 54525952);
  unsigned short* hdM     = (unsigned short*)(ws + RA + 54788096);
  unsigned short* cH      = (unsigned short*)(ws + RA + 55050240);
  unsigned short* cM      = (unsigned short*)(ws + RA + 56098816);

  // ---- Region B (31.85 MB): phase1 h2p splits; phase2 Bp_fc/pred ----
  size_t RB = alloc(31850496);
  unsigned short* h2pH = (unsigned short*)(ws + RB);
  unsigned short* h2pM = (unsigned short*)(ws + RB + 10616832);
  unsigned short* h2pL = (unsigned short*)(ws + RB + 21233664);
  unsigned short* Bp_fc = (unsigned short*)(ws + RB);             // 25.17 MB
  unsigned short* pH    = (unsigned short*)(ws + RB + 28311552);
  unsigned short* pM    = (unsigned short*)(ws + RB + 29360128);
  unsigned short* pL    = (unsigned short*)(ws + RB + 30408704);

  // ---- Region C (12.58 MB): phase1 h3 splits; phase2 Bp_ffc/hfc ----
  size_t RC = alloc(12582912);
  unsigned short* h3H = (unsigned short*)(ws + RC);
  unsigned short* h3M = (unsigned short*)(ws + RC + 4194304);
  unsigned short* h3L = (unsigned short*)(ws + RC + 8388608);
  unsigned short* Bp_ffc = (unsigned short*)(ws + RC);            // 6.29 MB (after fc)
  unsigned short* hfcH   = (unsigned short*)(ws + RC + 6291456);
  unsigned short* hfcM   = (unsigned short*)(ws + RC + 6553600);
  unsigned short* hfcL   = (unsigned short*)(ws + RC + 6815744);

  // ---- dedicated (lifetime spans whole run) ----
  unsigned short* eB     = (unsigned short*)(ws + alloc(3145728));
  unsigned short* Bp_dfc = (unsigned short*)(ws + alloc(4194304));
  unsigned short* Bp_d2  = (unsigned short*)(ws + alloc(2097152));
  float* n2buf   = (float*)(ws + alloc(32768));
  float* pbd     = (float*)(ws + alloc(262144));
  int*   pbk     = (int*)  (ws + alloc(262144));
  unsigned short* Wp2H = (unsigned short*)(ws + alloc(196608));
  unsigned short* Wp2M = Wp2H + 32768;
  unsigned short* Wp2L = Wp2M + 32768;
  unsigned short* Wp3H = (unsigned short*)(ws + alloc(786432));
  unsigned short* Wp3M = Wp3H + 131072;
  unsigned short* Wp3L = Wp3M + 131072;
  (void)ws_size; (void)in_sizes; (void)n_in; (void)out_size;

  // all input-only prep in one launch
  k_prep_early<<<PB7, 256, 0, stream>>>(
      enc_w2, enc_w3, embeds, dec_fc_w, dec_w2, h1pH, h2pH,
      Wp2H, Wp2M, Wp2L, Wp3H, Wp3M, Wp3L, eB, n2buf, Bp_dfc, Bp_d2);

  k_conv1<<<8192, 256, 0, stream>>>(x, enc_w1, enc_b1, h1pH, h1pM, h1pL);
  k_conv2s<<<256, 1024, 0, stream>>>(h1pH, h1pM, h1pL, Wp2H, Wp2M, Wp2L,
                                     enc_b2, h2pH, h2pM, h2pL);
  k_conv3s<<<dim3(128, 2), 512, 0, stream>>>(h2pH, h2pM, h2pL,
                                             Wp3H, Wp3M, Wp3L, partials);
  // sumrelu(conv3) + bprep fc in one launch
  k_prep_fc<<<FB1, 256, 0, stream>>>(partials, enc_b3, h3H, h3M, h3L,
                                     fc_w, Bp_fc);

  // fc: (256x512) = h3(256x8192) @ fc_w, NP=3, S=16
  k_mgemm<3, 4><<<dim3(4, 8, 16), 256, 0, stream>>>(
      h3H, h3M, h3L, Bp_fc, partials, fc_b, 256, 512, 8192, 511);
  // bprep ffc + bprep_ct dec_w1 in one launch
  k_prep_w2<<<WB1, 256, 0, stream>>>(ffc_w, Bp_ffc, dec_w1, Bp_d1);
  k_sumrelu3<3><<<512, 256, 0, stream>>>(partials, fc_b, hfcH, hfcM, hfcL,
                                         131072, 511, 16);
  // ffc: (256x2048), NP=3, S=4 -> pred splits
  k_mgemm<3, 4><<<dim3(4, 32, 4), 256, 0, stream>>>(
      hfcH, hfcM, hfcL, Bp_ffc, partials, ffc_b, 256, 2048, 512, 2047);
  k_sumrelu3<3><<<2048, 256, 0, stream>>>(partials, ffc_b, pH, pM, pL,
                                          524288, 2047, 4);

  // VQ
  k_vqmfma3<<<dim3(64, 8), 256, 0, stream>>>(pH, pM, pL, eB, n2buf, pbd, pbk);
  k_vqgather<<<2048, 256, 0, stream>>>(pbd, pbk, embeds, cH, cM);

  // dec_fc: (256x512), NP=2, S=16
  k_mgemm<2, 4><<<dim3(4, 8, 16), 256, 0, stream>>>(
      cH, cM, nullptr, Bp_dfc, partials, dec_fc_b, 256, 512, 2048, 511);
  k_sumrelu3<2><<<512, 256, 0, stream>>>(partials, dec_fc_b, hdH, hdM, nullptr,
                                         131072, 511, 16);

  // dec1: (256x4096), NP=2, S=2
  k_mgemm<2, 4><<<dim3(4, 64, 2), 256, 0, stream>>>(
      hdH, hdM, nullptr, Bp_d1, partials, dec_b1, 256, 4096, 512, 255);
  k_sumrelu3<2><<<4096, 256, 0, stream>>>(partials, dec_b1, d1H, d1M, nullptr,
                                          1048576, 255, 2);

  // dec2: (4096x2048), NP=2, S=1 -> fp32 d2buf (+bias+relu)
  k_mgemm<2, 8><<<dim3(64, 16, 1), 256, 0, stream>>>(
      d1H, d1M, nullptr, Bp_d2, d2buf, dec_b2, 4096, 2048, 256, 127);

  // dec3 -> final output (no relu)
  k_dec3<<<4096, 256, 0, stream>>>(d2buf, dec_w3, dec_b3, outp);
}

// Round 4
// 425.568 us; speedup vs baseline: 1.0877x; 1.0147x over previous
//
#include <hip/hip_runtime.h>
#include <cfloat>

// =====================================================================
// VQ-VAE forward.
// R13: k_vqmfma3 -> LDS-staged eB (third application of the R10/R11
// recipe). R12 counters: vqmfma3 49.5us, MfmaUtil 40%, HBM 3.8% -- all
// 4 waves/block (and all 64 blocks/z) re-read identical 24 KB/kt eB
// fragments from L1/L2 (~786 MB traffic for a 3 MB tensor). Now: per-kt
// slice double-buffered in 48 KB LDS (reg-prefetch kt+1 during compute,
// one barrier/kt), shared by the block's 4 waves. MFMA floor 24.8us;
// predict ~28-32us. Bit-identical MFMA order -> same numerics.
//
// conv_transpose (transpose_kernel=False) => flipped kernel:
//   out[4i+r, 4j+u, o] = sum_c in[i,j,c] * w[3-r, 3-u, c, o]
// Encoder convs: SAME pad = (1,1) -> padded split inputs.
// Precision: NP=3 split (6 MFMA products) ~= fp32 (2^-25 rel) for
// everything feeding the argmin; NP=2 (3 products, ~1e-5 rel) for the
// decoder (threshold 2.5e-4).
// =====================================================================

typedef short bf16x8 __attribute__((ext_vector_type(8)));
typedef float f32x4 __attribute__((ext_vector_type(4)));
#define MFMA16(a, b, c) __builtin_amdgcn_mfma_f32_16x16x32_bf16(a, b, c, 0, 0, 0)

__device__ inline unsigned short f2bf(float x) {  // RNE, inputs finite
  unsigned u = __float_as_uint(x);
  u += 0x7fffu + ((u >> 16) & 1u);
  return (unsigned short)(u >> 16);
}
__device__ inline float bf2f(unsigned short h) {
  return __uint_as_float(((unsigned)h) << 16);
}
__device__ inline void split3v(float v, unsigned short& hb, unsigned short& mb,
                               unsigned short& lb) {
  hb = f2bf(v);
  float r1 = v - bf2f(hb);
  mb = f2bf(r1);
  lb = f2bf(r1 - bf2f(mb));
}

// ---------------- fused input-only prep (one launch) ----------------
// segments: zborder h1p | zborder h2p | wprep2 | wprep3 | eprep | norm2 |
// bprep dec_fc (NP2) | bprep_ct dec_w2 (NP2)
#define PB0 12672
#define PB1 (PB0 + 13056)
#define PB2 (PB1 + 128)
#define PB3 (PB2 + 512)
#define PB4 (PB3 + 2048)
#define PB5 (PB4 + 32)
#define PB6 (PB5 + 4096)
#define PB7 (PB6 + 2048)
__global__ __launch_bounds__(256) void k_prep_early(
    const float* __restrict__ enc_w2, const float* __restrict__ enc_w3,
    const float* __restrict__ embeds, const float* __restrict__ dec_fc_w,
    const float* __restrict__ dec_w2, unsigned short* __restrict__ h1base,
    unsigned short* __restrict__ h2base, unsigned short* __restrict__ Wp2H,
    unsigned short* __restrict__ Wp2M, unsigned short* __restrict__ Wp2L,
    unsigned short* __restrict__ Wp3H, unsigned short* __restrict__ Wp3M,
    unsigned short* __restrict__ Wp3L, unsigned short* __restrict__ eB,
    float* __restrict__ n2, unsigned short* __restrict__ Bp_dfc,
    unsigned short* __restrict__ Bp_d2) {
  int blk = blockIdx.x;
  int t = threadIdx.x;
  if (blk < PB0) {                       // zborder h1p (W=34, C=32)
    int li = blk * 256 + t;
    int bc = li & 8191;
    int rest = li >> 13;                 // i + 132*plane
    int i = rest % 132, plane = rest / 132;
    int b = bc >> 5, c = bc & 31;
    int row, col;
    if (i < 34) { row = 0; col = i; }
    else if (i < 68) { row = 33; col = i - 34; }
    else { int j = i - 68; row = 1 + (j >> 1); col = (j & 1) ? 33 : 0; }
    h1base[(size_t)plane * 9469952 + ((size_t)(b * 34 + row) * 34 + col) * 32 + c] = 0;
  } else if (blk < PB1) {                // zborder h2p (W=18, C=64)
    int li = (blk - PB0) * 256 + t;
    int bc = li & 16383;
    int rest = li >> 14;
    int i = rest % 68, plane = rest / 68;
    int b = bc >> 6, c = bc & 63;
    int row, col;
    if (i < 18) { row = 0; col = i; }
    else if (i < 36) { row = 17; col = i - 18; }
    else { int j = i - 36; row = 1 + (j >> 1); col = (j & 1) ? 17 : 0; }
    h2base[(size_t)plane * 5308416 + ((size_t)(b * 18 + row) * 18 + col) * 64 + c] = 0;
  } else if (blk < PB2) {                // wprep2
    int idx = (blk - PB1) * 256 + t;     // 32768
    int j = idx & 7, lane = (idx >> 3) & 63, nt = (idx >> 9) & 3, s = idx >> 11;
    int ci = ((lane >> 4) << 3) + j, co = (nt << 4) + (lane & 15);
    unsigned short hb, mb, lb;
    split3v(enc_w2[(s * 32 + ci) * 64 + co], hb, mb, lb);
    Wp2H[idx] = hb; Wp2M[idx] = mb; Wp2L[idx] = lb;
  } else if (blk < PB3) {                // wprep3
    int idx = (blk - PB2) * 256 + t;     // 131072
    int j = idx & 7, lane = (idx >> 3) & 63, ks = (idx >> 9) & 1;
    int nt = (idx >> 10) & 3, ch = (idx >> 12) & 1, s = idx >> 13;
    int ci = ks * 32 + ((lane >> 4) << 3) + j;
    int co = ch * 64 + (nt << 4) + (lane & 15);
    unsigned short hb, mb, lb;
    split3v(enc_w3[(s * 64 + ci) * 128 + co], hb, mb, lb);
    Wp3H[idx] = hb; Wp3M[idx] = mb; Wp3L[idx] = lb;
  } else if (blk < PB4) {                // eprep (one read -> 3 writes)
    int idx = (blk - PB3) * 256 + t;     // 524,288
    int j = idx & 7, lane = (idx >> 3) & 63;
    int f = idx >> 9;                    // (kt*2+ks)*4+nt
    int nt = f & 3, ks = (f >> 2) & 1, kt = f >> 3;
    int code = kt * 64 + nt * 16 + (lane & 15);
    int k = ks * 32 + ((lane >> 4) << 3) + j;
    unsigned short hb, mb, lb;
    split3v(embeds[(size_t)code * 64 + k], hb, mb, lb);
    size_t base = (size_t)f * 1536 + lane * 8 + j;
    eB[base] = hb; eB[base + 512] = mb; eB[base + 1024] = lb;
  } else if (blk < PB5) {                // norm2
    int k = (blk - PB4) * 256 + t;       // 8192
    const float4* p = (const float4*)(embeds + (size_t)k * 64);
    float s0 = 0, s1 = 0, s2 = 0, s3 = 0;
#pragma unroll
    for (int j = 0; j < 16; ++j) {
      float4 v = p[j];
      s0 = fmaf(v.x, v.x, s0); s1 = fmaf(v.y, v.y, s1);
      s2 = fmaf(v.z, v.z, s2); s3 = fmaf(v.w, v.w, s3);
    }
    n2[k] = (s0 + s1) + (s2 + s3);
  } else if (blk < PB6) {                // bprep dec_fc NP=2 (K=2048,N=512)
    int idx = (blk - PB5) * 256 + t;     // 1,048,576
    int j = idx & 7, lane = (idx >> 3) & 63;
    int f = idx >> 9;
    int ntg = f & 31;                    // NT=32
    int kt = f >> 5;                     // KT=64
    int k = kt * 32 + ((lane >> 4) << 3) + j;
    int n = ntg * 16 + (lane & 15);
    unsigned short hb, mb, lb;
    split3v(dec_fc_w[(size_t)k * 512 + n], hb, mb, lb);
    Bp_dfc[idx] = hb; Bp_dfc[idx + 1048576] = mb;
  } else if (blk < PB7) {                // bprep_ct dec_w2 NP=2 (K=256,N=2048,CO=128)
    int idx = (blk - PB6) * 256 + t;     // 524,288
    int j = idx & 7, lane = (idx >> 3) & 63;
    int f = idx >> 9;
    int ntg = f & 127;                   // NT=128
    int kt = f >> 7;                     // KT=8
    int k = kt * 32 + ((lane >> 4) << 3) + j;
    int n = ntg * 16 + (lane & 15);
    int o = n & 127, ru = n >> 7;
    int r = ru >> 2, u = ru & 3;
    int sf = (3 - r) * 4 + (3 - u);
    unsigned short hb, mb, lb;
    split3v(dec_w2[(((size_t)sf * 256 + k) << 7) + o], hb, mb, lb);
    Bp_d2[idx] = hb; Bp_d2[idx + 524288] = mb;
  }
}

// ---------------- conv1: x(256,64,64,1) -> h1p split padded (256,34,34,32) ----
__global__ __launch_bounds__(256) void k_conv1(const float* __restrict__ x,
                                               const float* __restrict__ w,
                                               const float* __restrict__ bias,
                                               unsigned short* __restrict__ oH,
                                               unsigned short* __restrict__ oM,
                                               unsigned short* __restrict__ oL) {
  int b = blockIdx.x >> 5;          // 8192 blocks: (b, y)
  int y = blockIdx.x & 31;
  int t = threadIdx.x;
  int c = t & 31;
  int xg = t >> 5;                  // 0..7, 4 x-positions each
  float acc[4] = {0.f, 0.f, 0.f, 0.f};
  for (int dy = 0; dy < 4; ++dy) {
    int iy = 2 * y + dy - 1;
    if (iy < 0 || iy >= 64) continue;
    const float* xrow = x + ((size_t)b * 64 + iy) * 64;
    for (int dx = 0; dx < 4; ++dx) {
      float wv = w[(dy * 4 + dx) * 32 + c];
#pragma unroll
      for (int i = 0; i < 4; ++i) {
        int ix = 8 * xg + 2 * i + dx - 1;
        float v = (ix >= 0 && ix < 64) ? xrow[ix] : 0.f;
        acc[i] = fmaf(v, wv, acc[i]);
      }
    }
  }
  float bv = bias[c];
#pragma unroll
  for (int i = 0; i < 4; ++i) {
    float v = acc[i] + bv;
    v = v > 0.f ? v : 0.f;
    unsigned short hb, mb, lb;
    split3v(v, hb, mb, lb);
    size_t o = ((size_t)(b * 34 + y + 1) * 34 + (4 * xg + i + 1)) * 32 + c;
    oH[o] = hb; oM[o] = mb; oL[o] = lb;
  }
}

// ---------------- conv2 MFMA, LDS-staged weights ----------------
// 1024-thread blocks (16 waves), 256 blocks = 1 block/CU, 4 waves/SIMD.
// Bs holds one s-half of the NP=3 split weights: 3 planes x 8 s x 4 nt
// x 64 lanes x 8 shorts = 49152 shorts = 96 KB.
__global__ __launch_bounds__(1024, 4) void k_conv2s(
    const unsigned short* __restrict__ aH, const unsigned short* __restrict__ aM,
    const unsigned short* __restrict__ aL, const unsigned short* __restrict__ wH,
    const unsigned short* __restrict__ wM, const unsigned short* __restrict__ wL,
    const float* __restrict__ bias, unsigned short* __restrict__ oH,
    unsigned short* __restrict__ oM, unsigned short* __restrict__ oL) {
  __shared__ unsigned short Bs[49152];      // 96 KB
  int t = threadIdx.x;
  int wave = t >> 6, lane = t & 63;
  int l15 = lane & 15, quad = lane >> 4;
  int m0 = blockIdx.x * 256 + wave * 16;    // 256 blocks x 256 px
  int p = m0 + l15;
  int b = p >> 8, y = (p >> 4) & 15, x = p & 15;
  f32x4 acc[4] = {};
#pragma unroll
  for (int hf = 0; hf < 2; ++hf) {
    if (hf) __syncthreads();                // all waves done reading half 0
    // stage half hf: per plane 16384 shorts (= s in [8hf, 8hf+8))
    {
      const unsigned short* s0 = wH + hf * 16384;
      const unsigned short* s1 = wM + hf * 16384;
      const unsigned short* s2 = wL + hf * 16384;
#pragma unroll
      for (int i = 0; i < 2; ++i) {
        int o8 = (i * 1024 + t) * 8;
        *(bf16x8*)(Bs + o8)         = *(const bf16x8*)(s0 + o8);
        *(bf16x8*)(Bs + 16384 + o8) = *(const bf16x8*)(s1 + o8);
        *(bf16x8*)(Bs + 32768 + o8) = *(const bf16x8*)(s2 + o8);
      }
    }
    __syncthreads();
#pragma unroll 4
    for (int sl = 0; sl < 8; ++sl) {
      int s = hf * 8 + sl;
      int dy = s >> 2, dx = s & 3;
      size_t aoff = ((size_t)(b * 34 + 2 * y + dy) * 34 + (2 * x + dx)) * 32 + quad * 8;
      bf16x8 ah = *(const bf16x8*)(aH + aoff);
      bf16x8 am = *(const bf16x8*)(aM + aoff);
      bf16x8 al = *(const bf16x8*)(aL + aoff);
#pragma unroll
      for (int nt = 0; nt < 4; ++nt) {
        const unsigned short* bp = Bs + ((sl * 4 + nt) * 64 + lane) * 8;
        bf16x8 bh = *(const bf16x8*)(bp);
        bf16x8 bm = *(const bf16x8*)(bp + 16384);
        bf16x8 bl = *(const bf16x8*)(bp + 32768);
        acc[nt] = MFMA16(am, bm, acc[nt]);
        acc[nt] = MFMA16(ah, bl, acc[nt]);
        acc[nt] = MFMA16(al, bh, acc[nt]);
        acc[nt] = MFMA16(ah, bm, acc[nt]);
        acc[nt] = MFMA16(am, bh, acc[nt]);
        acc[nt] = MFMA16(ah, bh, acc[nt]);
      }
    }
  }
#pragma unroll
  for (int r = 0; r < 4; ++r) {
    int pp = m0 + quad * 4 + r;
    int b2 = pp >> 8, yo = (pp >> 4) & 15, xo = pp & 15;
    size_t obase = ((size_t)(b2 * 18 + yo + 1) * 18 + (xo + 1)) * 64;
#pragma unroll
    for (int nt = 0; nt < 4; ++nt) {
      int co = nt * 16 + l15;
      float v = acc[nt][r] + bias[co];
      v = v > 0.f ? v : 0.f;
      unsigned short hb, mb, lb;
      split3v(v, hb, mb, lb);
      oH[obase + co] = hb; oM[obase + co] = mb; oL[obase + co] = lb;
    }
  }
}

// ---------------- conv3 MFMA, LDS-staged weights, mt=2 ----------------
// 512-thread blocks (8 waves = 4 mgroups x 2 ch), grid (128, 2): block =
// 128 px x 128 co at one z-half (8 s-steps). Per-s weight slice is
// contiguous in Wp3 (8192 shorts/plane = 48 KB for 3 planes); double-
// buffered in 96 KB LDS, reg-prefetch of s+1 overlapped with compute,
// one barrier per s. Wave = 32 px x 64 co (mt=2) so each B fragment
// feeds 2x MFMAs. Output: fp32 partials [z][16384][128] (same as R10).
__global__ __launch_bounds__(512, 2) void k_conv3s(
    const unsigned short* __restrict__ aH, const unsigned short* __restrict__ aM,
    const unsigned short* __restrict__ aL, const unsigned short* __restrict__ wH,
    const unsigned short* __restrict__ wM, const unsigned short* __restrict__ wL,
    float* __restrict__ part) {
  __shared__ unsigned short Bs[2][24576];   // [dbuf][plane*8192 + frag] 96 KB
  int t = threadIdx.x;
  int wave = t >> 6, lane = t & 63;
  int l15 = lane & 15, quad = lane >> 4;
  int ch = wave & 1, mg = wave >> 1;
  int m0 = blockIdx.x * 128 + mg * 32;
  int z = blockIdx.y;
  f32x4 acc[2][4] = {};
  {  // stage s = z*8 into buf 0
    const unsigned short* srcH = wH + (size_t)(z * 8) * 8192;
    const unsigned short* srcM = wM + (size_t)(z * 8) * 8192;
    const unsigned short* srcL = wL + (size_t)(z * 8) * 8192;
#pragma unroll
    for (int i = 0; i < 2; ++i) {
      int o8 = (i * 512 + t) * 8;
      *(bf16x8*)(&Bs[0][o8])         = *(const bf16x8*)(srcH + o8);
      *(bf16x8*)(&Bs[0][8192 + o8])  = *(const bf16x8*)(srcM + o8);
      *(bf16x8*)(&Bs[0][16384 + o8]) = *(const bf16x8*)(srcL + o8);
    }
  }
  __syncthreads();
#pragma unroll 2
  for (int si = 0; si < 8; ++si) {
    int s = z * 8 + si;
    int cur = si & 1, nxt = cur ^ 1;
    bf16x8 stg[6];
    if (si < 7) {                           // prefetch s+1 into regs
      const unsigned short* srcH = wH + (size_t)(s + 1) * 8192;
      const unsigned short* srcM = wM + (size_t)(s + 1) * 8192;
      const unsigned short* srcL = wL + (size_t)(s + 1) * 8192;
#pragma unroll
      for (int i = 0; i < 2; ++i) {
        int o8 = (i * 512 + t) * 8;
        stg[i]     = *(const bf16x8*)(srcH + o8);
        stg[2 + i] = *(const bf16x8*)(srcM + o8);
        stg[4 + i] = *(const bf16x8*)(srcL + o8);
      }
    }
    int dy = s >> 2, dx = s & 3;
    bf16x8 ah[2][2], am[2][2], al[2][2];    // [mt][ks]
#pragma unroll
    for (int mt = 0; mt < 2; ++mt) {
      int p = m0 + mt * 16 + l15;
      int b = p >> 6, y = (p >> 3) & 7, x = p & 7;
      size_t base = ((size_t)(b * 18 + 2 * y + dy) * 18 + (2 * x + dx)) * 64 + quad * 8;
#pragma unroll
      for (int ks = 0; ks < 2; ++ks) {
        ah[mt][ks] = *(const bf16x8*)(aH + base + ks * 32);
        am[mt][ks] = *(const bf16x8*)(aM + base + ks * 32);
        al[mt][ks] = *(const bf16x8*)(aL + base + ks * 32);
      }
    }
#pragma unroll
    for (int nt = 0; nt < 4; ++nt)
#pragma unroll
      for (int ks = 0; ks < 2; ++ks) {
        const unsigned short* bp =
            &Bs[cur][((ch * 4 + nt) * 2 + ks) * 512 + lane * 8];
        bf16x8 bh = *(const bf16x8*)(bp);
        bf16x8 bm = *(const bf16x8*)(bp + 8192);
        bf16x8 bl = *(const bf16x8*)(bp + 16384);
#pragma unroll
        for (int mt = 0; mt < 2; ++mt) {
          acc[mt][nt] = MFMA16(am[mt][ks], bm, acc[mt][nt]);
          acc[mt][nt] = MFMA16(ah[mt][ks], bl, acc[mt][nt]);
          acc[mt][nt] = MFMA16(al[mt][ks], bh, acc[mt][nt]);
          acc[mt][nt] = MFMA16(ah[mt][ks], bm, acc[mt][nt]);
          acc[mt][nt] = MFMA16(am[mt][ks], bh, acc[mt][nt]);
          acc[mt][nt] = MFMA16(ah[mt][ks], bh, acc[mt][nt]);
        }
      }
    if (si < 7) {                           // write prefetched s+1
#pragma unroll
      for (int i = 0; i < 2; ++i) {
        int o8 = (i * 512 + t) * 8;
        *(bf16x8*)(&Bs[nxt][o8])         = stg[i];
        *(bf16x8*)(&Bs[nxt][8192 + o8])  = stg[2 + i];
        *(bf16x8*)(&Bs[nxt][16384 + o8]) = stg[4 + i];
      }
    }
    __syncthreads();
  }
  float* Cp = part + (size_t)z * 2097152;
#pragma unroll
  for (int mt = 0; mt < 2; ++mt)
#pragma unroll
    for (int nt = 0; nt < 4; ++nt) {
      int co = ch * 64 + nt * 16 + l15;
#pragma unroll
      for (int r = 0; r < 4; ++r) {
        int pp = m0 + mt * 16 + quad * 4 + r;
        Cp[(size_t)pp * 128 + co] = acc[mt][nt][r];
      }
    }
}

// ---------------- fused: sumrelu(conv3) + bprep fc (NP=3) ----------------
#define FB0 8192
#define FB1 (FB0 + 16384)
__global__ __launch_bounds__(256) void k_prep_fc(
    const float* __restrict__ part, const float* __restrict__ enc_b3,
    unsigned short* __restrict__ h3H, unsigned short* __restrict__ h3M,
    unsigned short* __restrict__ h3L, const float* __restrict__ fc_w,
    unsigned short* __restrict__ Bp_fc) {
  int blk = blockIdx.x;
  int t = threadIdx.x;
  if (blk < FB0) {                       // sumrelu conv3: MN=2097152, S=2
    int idx = blk * 256 + t;
    float s = part[idx] + part[2097152 + idx] + enc_b3[idx & 127];
    s = s > 0.f ? s : 0.f;
    unsigned short hb, mb, lb;
    split3v(s, hb, mb, lb);
    h3H[idx] = hb; h3M[idx] = mb; h3L[idx] = lb;
  } else {                               // bprep fc: K=8192, N=512 (KT=256,NT=32)
    int idx = (blk - FB0) * 256 + t;     // 4,194,304
    int j = idx & 7, lane = (idx >> 3) & 63;
    int f = idx >> 9;
    int ntg = f & 31;
    int kt = f >> 5;
    int k = kt * 32 + ((lane >> 4) << 3) + j;
    int n = ntg * 16 + (lane & 15);
    unsigned short hb, mb, lb;
    split3v(fc_w[(size_t)k * 512 + n], hb, mb, lb);
    Bp_fc[idx] = hb; Bp_fc[idx + 4194304] = mb; Bp_fc[idx + 8388608] = lb;
  }
}

// ---------------- fused: bprep ffc (NP=3) + bprep_ct dec_w1 (NP=2) ----------
#define WB0 4096
#define WB1 (WB0 + 8192)
__global__ __launch_bounds__(256) void k_prep_w2(
    const float* __restrict__ ffc_w, unsigned short* __restrict__ Bp_ffc,
    const float* __restrict__ dec_w1, unsigned short* __restrict__ Bp_d1) {
  int blk = blockIdx.x;
  int t = threadIdx.x;
  if (blk < WB0) {                       // ffc: K=512, N=2048 (KT=16, NT=128)
    int idx = blk * 256 + t;             // 1,048,576
    int j = idx & 7, lane = (idx >> 3) & 63;
    int f = idx >> 9;
    int ntg = f & 127;
    int kt = f >> 7;
    int k = kt * 32 + ((lane >> 4) << 3) + j;
    int n = ntg * 16 + (lane & 15);
    unsigned short hb, mb, lb;
    split3v(ffc_w[(size_t)k * 2048 + n], hb, mb, lb);
    Bp_ffc[idx] = hb; Bp_ffc[idx + 1048576] = mb; Bp_ffc[idx + 2097152] = lb;
  } else {                               // dec_w1 ct: K=512, N=4096, CO=256
    int idx = (blk - WB0) * 256 + t;     // 2,097,152
    int j = idx & 7, lane = (idx >> 3) & 63;
    int f = idx >> 9;
    int ntg = f & 255;                   // NT=256
    int kt = f >> 8;                     // KT=16
    int k = kt * 32 + ((lane >> 4) << 3) + j;
    int n = ntg * 16 + (lane & 15);
    int o = n & 255, ru = n >> 8;
    int r = ru >> 2, u = ru & 3;
    int sf = (3 - r) * 4 + (3 - u);
    unsigned short hb, mb, lb;
    split3v(dec_w1[(((size_t)sf * 512 + k) << 8) + o], hb, mb, lb);
    Bp_d1[idx] = hb; Bp_d1[idx + 2097152] = mb;
  }
}

// ---------------- generic split-bf16 MFMA GEMM ----------------
template <int NP, int NTW>
__global__ __launch_bounds__(256) void k_mgemm(
    const unsigned short* __restrict__ A0, const unsigned short* __restrict__ A1,
    const unsigned short* __restrict__ A2, const unsigned short* __restrict__ Bp,
    float* __restrict__ C, const float* __restrict__ bias,
    int M, int N, int K, int bmask) {
  int S = gridDim.z;
  int Kc = K / S;
  int t = threadIdx.x;
  int wave = t >> 6, lane = t & 63;
  int l15 = lane & 15, quad = lane >> 4;
  int m0 = blockIdx.x * 64 + wave * 16;
  int n0 = blockIdx.y * (16 * NTW);
  int KT = K >> 5, NT = N >> 4;
  int kt0 = (blockIdx.z * Kc) >> 5;
  int ktn = Kc >> 5;
  size_t sstride = (size_t)KT * NT * 512;
  const unsigned short* arow0 = A0 + (size_t)(m0 + l15) * K + quad * 8;
  const unsigned short* arow1 = A1 + (size_t)(m0 + l15) * K + quad * 8;
  const unsigned short* arow2 = nullptr;
  if constexpr (NP == 3) arow2 = A2 + (size_t)(m0 + l15) * K + quad * 8;
  f32x4 acc[NTW] = {};
  for (int kt = kt0; kt < kt0 + ktn; ++kt) {
    bf16x8 ah = *(const bf16x8*)(arow0 + kt * 32);
    bf16x8 am = *(const bf16x8*)(arow1 + kt * 32);
    bf16x8 al;
    if constexpr (NP == 3) al = *(const bf16x8*)(arow2 + kt * 32);
    const unsigned short* bbase =
        Bp + ((size_t)kt * NT + (n0 >> 4)) * 512 + lane * 8;
#pragma unroll
    for (int nt = 0; nt < NTW; ++nt) {
      const unsigned short* bp = bbase + nt * 512;
      bf16x8 bh = *(const bf16x8*)(bp);
      bf16x8 bm = *(const bf16x8*)(bp + sstride);
      if constexpr (NP == 3) {
        bf16x8 bl = *(const bf16x8*)(bp + 2 * sstride);
        acc[nt] = MFMA16(am, bm, acc[nt]);
        acc[nt] = MFMA16(ah, bl, acc[nt]);
        acc[nt] = MFMA16(al, bh, acc[nt]);
        acc[nt] = MFMA16(ah, bm, acc[nt]);
        acc[nt] = MFMA16(am, bh, acc[nt]);
        acc[nt] = MFMA16(ah, bh, acc[nt]);
      } else {
        acc[nt] = MFMA16(ah, bm, acc[nt]);
        acc[nt] = MFMA16(am, bh, acc[nt]);
        acc[nt] = MFMA16(ah, bh, acc[nt]);
      }
    }
  }
  if (S == 1) {
#pragma unroll
    for (int nt = 0; nt < NTW; ++nt) {
      int n = n0 + nt * 16 + l15;
      float bv = bias[n & bmask];
#pragma unroll
      for (int r = 0; r < 4; ++r) {
        int m = m0 + quad * 4 + r;
        float v = acc[nt][r] + bv;
        C[(size_t)m * N + n] = v > 0.f ? v : 0.f;
      }
    }
  } else {
    float* Cp = C + (size_t)blockIdx.z * M * N;
#pragma unroll
    for (int nt = 0; nt < NTW; ++nt) {
      int n = n0 + nt * 16 + l15;
#pragma unroll
      for (int r = 0; r < 4; ++r) {
        int m = m0 + quad * 4 + r;
        Cp[(size_t)m * N + n] = acc[nt][r];
      }
    }
  }
}

// sum k-split partials + bias + relu -> split planes
template <int NPOUT>
__global__ __launch_bounds__(256) void k_sumrelu3(
    const float* __restrict__ part, const float* __restrict__ bias,
    unsigned short* __restrict__ oH, unsigned short* __restrict__ oM,
    unsigned short* __restrict__ oL, int MN, int bmask, int S) {
  int idx = blockIdx.x * 256 + threadIdx.x;
  float s = 0.f;
  for (int z = 0; z < S; ++z) s += part[(size_t)z * MN + idx];
  s += bias[idx & bmask];
  s = s > 0.f ? s : 0.f;
  unsigned short hb = f2bf(s);
  float r1 = s - bf2f(hb);
  unsigned short mb = f2bf(r1);
  oH[idx] = hb; oM[idx] = mb;
  if constexpr (NPOUT == 3) oL[idx] = f2bf(r1 - bf2f(mb));
}

// ---------------- VQ ----------------
// k_vqmfma3: 32 m-rows per wave (2 A-sets); per-kt eB slice (24 KB)
// double-buffered in LDS, shared by the block's 4 waves (R13).
__global__ __launch_bounds__(256, 2) void k_vqmfma3(
    const unsigned short* __restrict__ pH, const unsigned short* __restrict__ pM,
    const unsigned short* __restrict__ pL, const unsigned short* __restrict__ eB,
    const float* __restrict__ n2, float* __restrict__ pbd, int* __restrict__ pbk) {
  __shared__ unsigned short Es[2][12288];   // 48 KB double-buffered
  int t = threadIdx.x;
  int wave = t >> 6, lane = t & 63;
  int l15 = lane & 15, quad = lane >> 4;
  int m0 = blockIdx.x * 128 + wave * 32;
  int z = blockIdx.y;
  bf16x8 ah[2][2], am[2][2], al[2][2];   // [mt][ks]
#pragma unroll
  for (int mt = 0; mt < 2; ++mt) {
    size_t arow = (size_t)(m0 + mt * 16 + l15) * 64 + quad * 8;
#pragma unroll
    for (int ks = 0; ks < 2; ++ks) {
      ah[mt][ks] = *(const bf16x8*)(pH + arow + ks * 32);
      am[mt][ks] = *(const bf16x8*)(pM + arow + ks * 32);
      al[mt][ks] = *(const bf16x8*)(pL + arow + ks * 32);
    }
  }
  float bd[2][4]; int bk[2][4];
#pragma unroll
  for (int mt = 0; mt < 2; ++mt)
#pragma unroll
    for (int r = 0; r < 4; ++r) { bd[mt][r] = FLT_MAX; bk[mt][r] = 0; }
  {  // stage kt = z*16 into buf 0
    const unsigned short* src = eB + (size_t)(z * 16) * 12288;
#pragma unroll
    for (int i = 0; i < 6; ++i) {
      int o8 = (i * 256 + t) * 8;
      *(bf16x8*)(&Es[0][o8]) = *(const bf16x8*)(src + o8);
    }
  }
  __syncthreads();
  for (int ki = 0; ki < 16; ++ki) {
    int kt = z * 16 + ki;
    int cur = ki & 1, nxt = cur ^ 1;
    bf16x8 stg[6];
    if (ki < 15) {                          // prefetch kt+1 into regs
      const unsigned short* src = eB + (size_t)(kt + 1) * 12288;
#pragma unroll
      for (int i = 0; i < 6; ++i) {
        int o8 = (i * 256 + t) * 8;
        stg[i] = *(const bf16x8*)(src + o8);
      }
    }
    const unsigned short* bb = &Es[cur][lane * 8];
    f32x4 acc[2][4] = {};
#pragma unroll
    for (int ks = 0; ks < 2; ++ks)
#pragma unroll
      for (int nt = 0; nt < 4; ++nt) {
        const unsigned short* bp = bb + ((ks * 4 + nt) * 3) * 512;
        bf16x8 bh = *(const bf16x8*)(bp);
        bf16x8 bm = *(const bf16x8*)(bp + 512);
        bf16x8 bl = *(const bf16x8*)(bp + 1024);
#pragma unroll
        for (int mt = 0; mt < 2; ++mt) {
          acc[mt][nt] = MFMA16(am[mt][ks], bm, acc[mt][nt]);
          acc[mt][nt] = MFMA16(ah[mt][ks], bl, acc[mt][nt]);
          acc[mt][nt] = MFMA16(al[mt][ks], bh, acc[mt][nt]);
          acc[mt][nt] = MFMA16(ah[mt][ks], bm, acc[mt][nt]);
          acc[mt][nt] = MFMA16(am[mt][ks], bh, acc[mt][nt]);
          acc[mt][nt] = MFMA16(ah[mt][ks], bh, acc[mt][nt]);
        }
      }
    int cb = kt * 64;
#pragma unroll
    for (int nt = 0; nt < 4; ++nt) {
      int code = cb + nt * 16 + l15;
      float nv = n2[code];
#pragma unroll
      for (int mt = 0; mt < 2; ++mt)
#pragma unroll
        for (int r = 0; r < 4; ++r) {
          float d = fmaf(-2.f, acc[mt][nt][r], nv);
          if (d < bd[mt][r]) { bd[mt][r] = d; bk[mt][r] = code; }
        }
    }
    if (ki < 15) {                          // write prefetched kt+1
#pragma unroll
      for (int i = 0; i < 6; ++i) {
        int o8 = (i * 256 + t) * 8;
        *(bf16x8*)(&Es[nxt][o8]) = stg[i];
      }
    }
    __syncthreads();
  }
#pragma unroll
  for (int mt = 0; mt < 2; ++mt)
#pragma unroll
    for (int r = 0; r < 4; ++r)
#pragma unroll
      for (int s = 1; s < 16; s <<= 1) {
        float od = __shfl_xor(bd[mt][r], s);
        int ok = __shfl_xor(bk[mt][r], s);
        if (od < bd[mt][r] || (od == bd[mt][r] && ok < bk[mt][r])) {
          bd[mt][r] = od; bk[mt][r] = ok;
        }
      }
  if (l15 == 0) {
#pragma unroll
    for (int mt = 0; mt < 2; ++mt)
#pragma unroll
      for (int r = 0; r < 4; ++r) {
        pbd[(size_t)z * 8192 + m0 + mt * 16 + quad * 4 + r] = bd[mt][r];
        pbk[(size_t)z * 8192 + m0 + mt * 16 + quad * 4 + r] = bk[mt][r];
      }
  }
}

// fused: reduce 8 z-groups per row (lex (d,k)) + gather -> 2-plane collected.
__global__ __launch_bounds__(256) void k_vqgather(const float* __restrict__ pbd,
                                                  const int* __restrict__ pbk,
                                                  const float* __restrict__ embeds,
                                                  unsigned short* __restrict__ cH,
                                                  unsigned short* __restrict__ cM) {
  int idx = blockIdx.x * 256 + threadIdx.x;   // 524288, 2048 blocks
  int m = idx >> 6;
  float bd = pbd[m]; int bk = pbk[m];
#pragma unroll
  for (int z = 1; z < 8; ++z) {
    float d = pbd[(size_t)z * 8192 + m]; int k = pbk[(size_t)z * 8192 + m];
    if (d < bd || (d == bd && k < bk)) { bd = d; bk = k; }
  }
  float v = embeds[(size_t)bk * 64 + (idx & 63)];
  unsigned short hb = f2bf(v);
  cH[idx] = hb;
  cM[idx] = f2bf(v - bf2f(hb));
}

// ---------------- dec3: d2buf(permuted) -> out(256,64,64), +bias, no relu ----
__global__ __launch_bounds__(256) void k_dec3(const float* __restrict__ d2buf,
                                              const float* __restrict__ w3,
                                              const float* __restrict__ b3,
                                              float* __restrict__ out) {
  __shared__ float sx[16 * 129];
  __shared__ float wT[128 * 16];
  int b = blockIdx.x >> 4;          // 4096 blocks: (b, y_in)
  int y = blockIdx.x & 15;
  int t = threadIdx.x;
#pragma unroll
  for (int j = 0; j < 8; ++j) {
    int idx = t + j * 256;          // 2048
    int xx = idx >> 7, c = idx & 127;
    size_t m2 = ((size_t)b * 4 + (y >> 2)) * 4 + (xx >> 2);
    sx[xx * 129 + c] = d2buf[m2 * 2048 + ((y & 3) * 4 + (xx & 3)) * 128 + c];
  }
#pragma unroll
  for (int j = 0; j < 8; ++j) {
    int idx = t + j * 256;
    int c = idx >> 4, ru = idx & 15;
    int R = ru >> 2, U = ru & 3;
    wT[c * 16 + ru] = w3[((3 - R) * 4 + (3 - U)) * 128 + c];
  }
  __syncthreads();
  int xx = t >> 4, ru = t & 15;
  float a0 = 0, a1 = 0, a2 = 0, a3 = 0;
#pragma unroll 8
  for (int c = 0; c < 128; c += 4) {
    a0 = fmaf(sx[xx * 129 + c + 0], wT[(c + 0) * 16 + ru], a0);
    a1 = fmaf(sx[xx * 129 + c + 1], wT[(c + 1) * 16 + ru], a1);
    a2 = fmaf(sx[xx * 129 + c + 2], wT[(c + 2) * 16 + ru], a2);
    a3 = fmaf(sx[xx * 129 + c + 3], wT[(c + 3) * 16 + ru], a3);
  }
  float acc = (a0 + a1) + (a2 + a3) + b3[0];
  int R = ru >> 2, U = ru & 3;
  out[((size_t)b * 64 + 4 * y + R) * 64 + 4 * xx + U] = acc;
}

// =====================================================================
extern "C" void kernel_launch(void* const* d_in, const int* in_sizes, int n_in,
                              void* d_out, int out_size, void* d_ws, size_t ws_size,
                              hipStream_t stream) {
  const float* x        = (const float*)d_in[0];
  const float* enc_w1   = (const float*)d_in[1];
  const float* enc_b1   = (const float*)d_in[2];
  const float* enc_w2   = (const float*)d_in[3];
  const float* enc_b2   = (const float*)d_in[4];
  const float* enc_w3   = (const float*)d_in[5];
  const float* enc_b3   = (const float*)d_in[6];
  const float* fc_w     = (const float*)d_in[7];
  const float* fc_b     = (const float*)d_in[8];
  const float* ffc_w    = (const float*)d_in[9];
  const float* ffc_b    = (const float*)d_in[10];
  const float* embeds   = (const float*)d_in[11];
  const float* dec_fc_w = (const float*)d_in[12];
  const float* dec_fc_b = (const float*)d_in[13];
  const float* dec_w1   = (const float*)d_in[14];
  const float* dec_b1   = (const float*)d_in[15];
  const float* dec_w2   = (const float*)d_in[16];
  const float* dec_b2   = (const float*)d_in[17];
  const float* dec_w3   = (const float*)d_in[18];
  const float* dec_b3   = (const float*)d_in[19];
  float* outp = (float*)d_out;

  char* ws = (char*)d_ws;
  size_t off = 0;
  auto alloc = [&](size_t bytes) { size_t r = off; off = (off + bytes + 255) & ~(size_t)255; return r; };

  // ---- Region A (57.15 MB): phase1 h1p splits; phase2 decoder/partials ----
  size_t RA = alloc(57147392);
  unsigned short* h1pH = (unsigned short*)(ws + RA);
  unsigned short* h1pM = (unsigned short*)(ws + RA + 18939904);
  unsigned short* h1pL = (unsigned short*)(ws + RA + 37879808);
  float* d2buf            = (float*)(ws + RA);                    // 33.55 MB
  float* partials         = (float*)(ws + RA + 33554432);         // <=16.78 MB
  unsigned short* Bp_d1   = (unsigned short*)(ws + RA + 41943040);// 8.39 MB
  unsigned short* d1H     = (unsigned short*)(ws + RA + 50331648);
  unsigned short* d1M     = (unsigned short*)(ws + RA + 52428800);
  unsigned short* hdH     = (unsigned short*)(ws + RA + 54525952);
  unsigned short* hdM     = (unsigned short*)(ws + RA + 54788096);
  unsigned short* cH      = (unsigned short*)(ws + RA + 55050240);
  unsigned short* cM      = (unsigned short*)(ws + RA + 56098816);

  // ---- Region B (31.85 MB): phase1 h2p splits; phase2 Bp_fc/pred ----
  size_t RB = alloc(31850496);
  unsigned short* h2pH = (unsigned short*)(ws + RB);
  unsigned short* h2pM = (unsigned short*)(ws + RB + 10616832);
  unsigned short* h2pL = (unsigned short*)(ws + RB + 21233664);
  unsigned short* Bp_fc = (unsigned short*)(ws + RB);             // 25.17 MB
  unsigned short* pH    = (unsigned short*)(ws + RB + 28311552);
  unsigned short* pM    = (unsigned short*)(ws + RB + 29360128);
  unsigned short* pL    = (unsigned short*)(ws + RB + 30408704);

  // ---- Region C (12.58 MB): phase1 h3 splits; phase2 Bp_ffc/hfc ----
  size_t RC = alloc(12582912);
  unsigned short* h3H = (unsigned short*)(ws + RC);
  unsigned short* h3M = (unsigned short*)(ws + RC + 4194304);
  unsigned short* h3L = (unsigned short*)(ws + RC + 8388608);
  unsigned short* Bp_ffc = (unsigned short*)(ws + RC);            // 6.29 MB (after fc)
  unsigned short* hfcH   = (unsigned short*)(ws + RC + 6291456);
  unsigned short* hfcM   = (unsigned short*)(ws + RC + 6553600);
  unsigned short* hfcL   = (unsigned short*)(ws + RC + 6815744);

  // ---- dedicated (lifetime spans whole run) ----
  unsigned short* eB     = (unsigned short*)(ws + alloc(3145728));
  unsigned short* Bp_dfc = (unsigned short*)(ws + alloc(4194304));
  unsigned short* Bp_d2  = (unsigned short*)(ws + alloc(2097152));
  float* n2buf   = (float*)(ws + alloc(32768));
  float* pbd     = (float*)(ws + alloc(262144));
  int*   pbk     = (int*)  (ws + alloc(262144));
  unsigned short* Wp2H = (unsigned short*)(ws + alloc(196608));
  unsigned short* Wp2M = Wp2H + 32768;
  unsigned short* Wp2L = Wp2M + 32768;
  unsigned short* Wp3H = (unsigned short*)(ws + alloc(786432));
  unsigned short* Wp3M = Wp3H + 131072;
  unsigned short* Wp3L = Wp3M + 131072;
  (void)ws_size; (void)in_sizes; (void)n_in; (void)out_size;

  // all input-only prep in one launch
  k_prep_early<<<PB7, 256, 0, stream>>>(
      enc_w2, enc_w3, embeds, dec_fc_w, dec_w2, h1pH, h2pH,
      Wp2H, Wp2M, Wp2L, Wp3H, Wp3M, Wp3L, eB, n2buf, Bp_dfc, Bp_d2);

  k_conv1<<<8192, 256, 0, stream>>>(x, enc_w1, enc_b1, h1pH, h1pM, h1pL);
  k_conv2s<<<256, 1024, 0, stream>>>(h1pH, h1pM, h1pL, Wp2H, Wp2M, Wp2L,
                                     enc_b2, h2pH, h2pM, h2pL);
  k_conv3s<<<dim3(128, 2), 512, 0, stream>>>(h2pH, h2pM, h2pL,
                                             Wp3H, Wp3M, Wp3L, partials);
  // sumrelu(conv3) + bprep fc in one launch
  k_prep_fc<<<FB1, 256, 0, stream>>>(partials, enc_b3, h3H, h3M, h3L,
                                     fc_w, Bp_fc);

  // fc: (256x512) = h3(256x8192) @ fc_w, NP=3, S=16
  k_mgemm<3, 4><<<dim3(4, 8, 16), 256, 0, stream>>>(
      h3H, h3M, h3L, Bp_fc, partials, fc_b, 256, 512, 8192, 511);
  // bprep ffc + bprep_ct dec_w1 in one launch
  k_prep_w2<<<WB1, 256, 0, stream>>>(ffc_w, Bp_ffc, dec_w1, Bp_d1);
  k_sumrelu3<3><<<512, 256, 0, stream>>>(partials, fc_b, hfcH, hfcM, hfcL,
                                         131072, 511, 16);
  // ffc: (256x2048), NP=3, S=4 -> pred splits
  k_mgemm<3, 4><<<dim3(4, 32, 4), 256, 0, stream>>>(
      hfcH, hfcM, hfcL, Bp_ffc, partials, ffc_b, 256, 2048, 512, 2047);
  k_sumrelu3<3><<<2048, 256, 0, stream>>>(partials, ffc_b, pH, pM, pL,
                                          524288, 2047, 4);

  // VQ
  k_vqmfma3<<<dim3(64, 8), 256, 0, stream>>>(pH, pM, pL, eB, n2buf, pbd, pbk);
  k_vqgather<<<2048, 256, 0, stream>>>(pbd, pbk, embeds, cH, cM);

  // dec_fc: (256x512), NP=2, S=16
  k_mgemm<2, 4><<<dim3(4, 8, 16), 256, 0, stream>>>(
      cH, cM, nullptr, Bp_dfc, partials, dec_fc_b, 256, 512, 2048, 511);
  k_sumrelu3<2><<<512, 256, 0, stream>>>(partials, dec_fc_b, hdH, hdM, nullptr,
                                         131072, 511, 16);

  // dec1: (256x4096), NP=2, S=2
  k_mgemm<2, 4><<<dim3(4, 64, 2), 256, 0, stream>>>(
      hdH, hdM, nullptr, Bp_d1, partials, dec_b1, 256, 4096, 512, 255);
  k_sumrelu3<2><<<4096, 256, 0, stream>>>(partials, dec_b1, d1H, d1M, nullptr,
                                          1048576, 255, 2);

  // dec2: (4096x2048), NP=2, S=1 -> fp32 d2buf (+bias+relu)
  k_mgemm<2, 8><<<dim3(64, 16, 1), 256, 0, stream>>>(
      d1H, d1M, nullptr, Bp_d2, d2buf, dec_b2, 4096, 2048, 256, 127);

  // dec3 -> final output (no relu)
  k_dec3<<<4096, 256, 0, stream>>>(d2buf, dec_w3, dec_b3, outp);
}